// Round 11
// baseline (80.351 us; speedup 1.0000x reference)
//
#include <hip/hip_runtime.h>
#include <hip/hip_bf16.h>
#include <math.h>

// Shapes (fixed): B=512, V=2, NX=1024, R=64, D=512, H=8, S=4, NC=2, HS=64, FIN=384

typedef unsigned short ushort_t;
using short8 = __attribute__((ext_vector_type(8))) short;
using f32x4  = __attribute__((ext_vector_type(4))) float;

__device__ __forceinline__ float gelu_f(float x) {
    float x3 = x*x*x;
    return 0.5f*x*(1.0f + tanhf(0.7978845608028654f*(x + 0.044715f*x3)));
}

__device__ __forceinline__ float wave_sum(float x) {
    #pragma unroll
    for (int m = 32; m >= 1; m >>= 1) x += __shfl_xor(x, m, 64);
    return x;
}

__device__ __forceinline__ ushort_t f2bf(float x) {
    unsigned u = __float_as_uint(x);
    unsigned r = (u + 0x7FFFu + ((u >> 16) & 1u)) >> 16;   // RNE
    return (ushort_t)r;
}
__device__ __forceinline__ float bf2f(ushort_t h) {
    return __uint_as_float(((unsigned)h) << 16);
}

// ---------------- pointer bundle ----------------
struct Ptrs {
    const float *a_n, *BC, *Phi, *Wq_w, *Wq_b, *Wk_w, *Wk_b, *Wv_w, *Wv_b,
                *attn_ow, *attn_ob, *proj_w, *proj_b,
                *ffn_w1, *ffn_w2, *ffn_w3, *ffn_b3, *ffn_ln_g, *ffn_ln_b,
                *a0_w, *a0_b, *a0_ln_g, *a0_ln_b, *alpha,
                *sb_w, *sb_b, *cm_w1, *cm_b1, *cm_w2, *cm_b2,
                *fu_w1, *fu_w2, *fu_w3, *fu_w4,
                *fu_b1, *fu_b2, *fu_b3, *fu_b4, *ffn_b1, *ffn_b2;
    float *opj, *u0, *u1, *u2, *pkq, *pqq, *pvo, *phirs, *bias2, *out;
    ushort_t *amap_bf, *h1_bf, *h2_bf, *fbuf_bf, *hA_bf, *hB_bf, *Abig, *Bphi;
};

// ---------------- cvt: Phi rows -> Bphi slab [2048][128] + phirs rowsums ----
// coff = column offset of the live slab (0 for v0, 64 for v1); other slab zeroed.
struct CvtDesc { const float* src; ushort_t* dst; int K, ldd, coff; };
struct CvtArgs { CvtDesc d[4]; int cum[5]; };

__device__ void cvt_dev(int tile, const CvtDesc& d, const Ptrs& p)
{
    const int t = threadIdx.x;
    const int row = t >> 2, q = t & 3;              // 64 rows/block, 4 thr/row
    const float* s = d.src + (long)(tile*64 + row)*64 + q*16;
    ushort_t* dst  = d.dst + (long)(tile*64 + row)*d.ldd + d.coff + q*16;
    ushort_t* dz   = d.dst + (long)(tile*64 + row)*d.ldd + (64 - d.coff) + q*16;
    float sum = 0.f;
    #pragma unroll
    for (int i = 0; i < 4; ++i) {
        float4 x = *(const float4*)(s + i*4);
        ushort4 w; w.x=f2bf(x.x); w.y=f2bf(x.y); w.z=f2bf(x.z); w.w=f2bf(x.w);
        *(ushort4*)(dst + i*4) = w;
        ushort4 z; z.x=0; z.y=0; z.z=0; z.w=0;
        *(ushort4*)(dz + i*4) = z;
        sum += x.x + x.y + x.z + x.w;
    }
    sum += __shfl_xor(sum, 1, 64);
    sum += __shfl_xor(sum, 2, 64);
    if (q == 0) p.phirs[d.K + tile*64 + row] = sum;
}

// ---------------- bf16 MFMA GEMM with on-the-fly fp32 B conversion ----------
// A bf16 [M][K] (row stride K); B fp32 [K][ldb] original layout, tile cols n0..n0+63.
// EPI: 0 = +bias, 1 = gelu(+bias). OUTBF: bf16 out else fp32.
__device__ void bgemm_f32b_dev(char* smem_,
    const ushort_t* __restrict__ A, const float* __restrict__ Bf,
    const float* __restrict__ bias, void* __restrict__ Cv,
    int m0, int n0, int K, int ldb, int ldc, int EPI, bool OUTBF)
{
    ushort_t* lds = (ushort_t*)smem_;   // [2][2][64][40]
    const int tid = threadIdx.x;
    const int w = tid >> 6, l = tid & 63;
    const int ml = l & 15, kg = l >> 4;
    const int srow = tid >> 2, sslot = tid & 3;
    const int kk = tid >> 3, ng = (tid & 7)*8;
    const ushort_t* Ag = A + (long)(m0 + srow)*K + sslot*8;
    const float* Bg = Bf + n0 + ng;
    auto L = [&](int buf, int ab, int row, int col) {
        return lds + (((buf*2 + ab)*64 + row)*40 + col);
    };
    auto wrB = [&](int buf, float4 b0, float4 b1) {
        ushort_t* bs = L(buf, 1, 0, 0);
        bs[(ng+0)*40 + kk] = f2bf(b0.x); bs[(ng+1)*40 + kk] = f2bf(b0.y);
        bs[(ng+2)*40 + kk] = f2bf(b0.z); bs[(ng+3)*40 + kk] = f2bf(b0.w);
        bs[(ng+4)*40 + kk] = f2bf(b1.x); bs[(ng+5)*40 + kk] = f2bf(b1.y);
        bs[(ng+6)*40 + kk] = f2bf(b1.z); bs[(ng+7)*40 + kk] = f2bf(b1.w);
    };
    f32x4 acc[4] = {};
    const int nt = K >> 5;
    int4 ra = *(const int4*)Ag;
    float4 rb0 = *(const float4*)(Bg + (long)kk*ldb);
    float4 rb1 = *(const float4*)(Bg + (long)kk*ldb + 4);
    *(int4*)L(0,0,srow,sslot*8) = ra;
    wrB(0, rb0, rb1);
    __syncthreads();
    for (int t = 0; t < nt; ++t) {
        const int cur = t & 1;
        if (t + 1 < nt) {
            ra  = *(const int4*)(Ag + (t+1)*32);
            rb0 = *(const float4*)(Bg + (long)((t+1)*32 + kk)*ldb);
            rb1 = *(const float4*)(Bg + (long)((t+1)*32 + kk)*ldb + 4);
        }
        short8 af = *(const short8*)L(cur,0,w*16 + ml,kg*8);
        #pragma unroll
        for (int f = 0; f < 4; ++f) {
            short8 bfr = *(const short8*)L(cur,1,f*16 + ml,kg*8);
            acc[f] = __builtin_amdgcn_mfma_f32_16x16x32_bf16(af, bfr, acc[f], 0, 0, 0);
        }
        if (t + 1 < nt) {
            *(int4*)L(cur^1,0,srow,sslot*8) = ra;
            wrB(cur^1, rb0, rb1);
            __syncthreads();
        }
    }
    float* Cf = (float*)Cv; ushort_t* Cb = (ushort_t*)Cv;
    const int mr = m0 + w*16 + kg*4;
    const int nc = n0 + ml;
    #pragma unroll
    for (int f = 0; f < 4; ++f) {
        const int n = nc + f*16;
        const float bs = bias[n];
        #pragma unroll
        for (int r = 0; r < 4; ++r) {
            float x = acc[f][r] + bs;
            if (EPI == 1) x = gelu_f(x);
            if (OUTBF) Cb[(long)(mr + r)*ldc + n] = f2bf(x);
            else       Cf[(long)(mr + r)*ldc + n] = x;
        }
    }
}

// ---------------- control: f = [sf(256), cf(128)] bf16 ----------------
__device__ void control_dev(char* smem, int b, const Ptrs& p)
{
    float* bc  = (float*)smem;        // 8
    float* cf1 = bc + 8;              // 64
    const int tid = threadIdx.x;
    if (tid < 6) bc[tid] = p.BC[b*6 + tid];
    __syncthreads();
    {
        int s = tid >> 6;
        p.fbuf_bf[(long)b*384 + tid] = f2bf(gelu_f(bc[s]*p.sb_w[tid] + p.sb_b[tid]));
    }
    if (tid < 64) {
        cf1[tid] = gelu_f(bc[4]*p.cm_w1[tid] + bc[5]*p.cm_w1[64+tid] + p.cm_b1[tid]);
    }
    __syncthreads();
    if (tid < 128) {
        float acc = p.cm_b2[tid];
        #pragma unroll 8
        for (int i = 0; i < 64; ++i) acc = fmaf(cf1[i], p.cm_w2[i*128 + tid], acc);
        p.fbuf_bf[(long)b*384 + 256 + tid] = f2bf(gelu_f(acc));
    }
}

// ---------------- a_map = LN(relu(a_n @ a0_w + a0_b)) bf16 ----------------
__device__ void a_map_dev(char* smem, int bx, int v, const Ptrs& p)
{
    float* arow = (float*)smem;       // [4][64]
    const int w = threadIdx.x >> 6, lane = threadIdx.x & 63;
    const int b = bx*4 + w;
    arow[w*64 + lane] = p.a_n[((long)b*2 + v)*64 + lane];
    __syncthreads();
    float acc = p.a0_b[v*64 + lane];
    #pragma unroll 8
    for (int rp = 0; rp < 64; ++rp)
        acc = fmaf(arow[w*64 + rp], p.a0_w[((long)v*64 + rp)*64 + lane], acc);
    float x = fmaxf(acc, 0.0f);
    float mu = wave_sum(x) * (1.0f/64.0f);
    float d = x - mu;
    float var = wave_sum(d*d) * (1.0f/64.0f);
    float y = d * rsqrtf(var + 1e-5f) * p.a0_ln_g[v*64 + lane] + p.a0_ln_b[v*64 + lane];
    p.amap_bf[((long)v*512 + b)*64 + lane] = f2bf(y);
}

// ---------------- opj[v,d] = sum_e attn_ow[v,d,e]*proj_w[v,e] ----------------
__device__ void opj_dev(int oi, const Ptrs& p)
{
    const int tid = threadIdx.x;
    const int v = oi >> 3, dc = oi & 7;
    const int d = dc*64 + (tid >> 2);
    const int e0 = (tid & 3)*128;
    const float* row = p.attn_ow + ((long)v*512 + d)*512 + e0;
    const float* pj  = p.proj_w + v*512 + e0;
    float s = 0.f;
    #pragma unroll 8
    for (int j = 0; j < 128; ++j) s = fmaf(row[j], pj[j], s);
    s += __shfl_xor(s, 1, 64);
    s += __shfl_xor(s, 2, 64);
    if ((tid & 3) == 0) p.opj[v*512 + d] = s;
}

// ---------------- u0/u1: per-head matvecs of Wk against Wq_w / Wq_b ----------------
__device__ void u01_dev(int i, const Ptrs& p)
{
    const int tid = threadIdx.x;
    const int w = tid >> 6, lane = tid & 63;
    const int v = i >> 4, c = i & 15;            // 64-row chunk
    const float* wq = p.Wq_w + v*512;
    const float* wb = p.Wq_b + v*512;
    for (int pass = 0; pass < 16; ++pass) {
        const int n = c*64 + pass*4 + w;
        const float* row = p.Wk_w + ((long)v*1024 + n)*512 + lane*8;
        float4 a = *(const float4*)row, b = *(const float4*)(row + 4);
        float s0 = 0.f, s1 = 0.f;
        #pragma unroll
        for (int j = 0; j < 8; ++j) {
            float x = (j < 4) ? ((const float*)&a)[j] : ((const float*)&b)[j-4];
            s0 = fmaf(x, wq[lane*8 + j], s0);
            s1 = fmaf(x, wb[lane*8 + j], s1);
        }
        s0 += __shfl_xor(s0,1,64); s0 += __shfl_xor(s0,2,64); s0 += __shfl_xor(s0,4,64);
        s1 += __shfl_xor(s1,1,64); s1 += __shfl_xor(s1,2,64); s1 += __shfl_xor(s1,4,64);
        if ((lane & 7) == 0) {
            const int h = lane >> 3;
            p.u0[((long)v*1024 + n)*8 + h] = s0;
            p.u1[((long)v*1024 + n)*8 + h] = s1;
        }
    }
}

// ---------------- u2: per-head matvec of Wv against opj ----------------
__device__ void u2_dev(int i, const Ptrs& p)
{
    const int tid = threadIdx.x;
    const int w = tid >> 6, lane = tid & 63;
    const int v = i >> 4, c = i & 15;
    const float* oj = p.opj + v*512;
    for (int pass = 0; pass < 16; ++pass) {
        const int n = c*64 + pass*4 + w;
        const float* row = p.Wv_w + ((long)v*1024 + n)*512 + lane*8;
        float4 a = *(const float4*)row, b = *(const float4*)(row + 4);
        float s0 = 0.f;
        #pragma unroll
        for (int j = 0; j < 8; ++j) {
            float x = (j < 4) ? ((const float*)&a)[j] : ((const float*)&b)[j-4];
            s0 = fmaf(x, oj[lane*8 + j], s0);
        }
        s0 += __shfl_xor(s0,1,64); s0 += __shfl_xor(s0,2,64); s0 += __shfl_xor(s0,4,64);
        if ((lane & 7) == 0) p.u2[((long)v*1024 + n)*8 + (lane >> 3)] = s0;
    }
}

// ---------------- kq/qq partials: Phi^T @ u0/u1 over an n-chunk of 128 ----------------
__device__ void kqqq_dev(int i, const Ptrs& p)
{
    const int tid = threadIdx.x;
    const int v = i >> 3, c = i & 7;
    const int r = tid & 63, hp = tid >> 6;
    const int h0 = hp*2, h1 = h0 + 1;
    float k0=0.f,k1=0.f,q0=0.f,q1=0.f;
    const float* Pb = p.Phi + ((long)v*1024 + c*128)*64 + r;
    const float* U0 = p.u0 + ((long)v*1024 + c*128)*8;
    const float* U1 = p.u1 + ((long)v*1024 + c*128)*8;
    #pragma unroll 4
    for (int n = 0; n < 128; ++n) {
        float phi = Pb[(long)n*64];
        k0 = fmaf(phi, U0[n*8+h0], k0); k1 = fmaf(phi, U0[n*8+h1], k1);
        q0 = fmaf(phi, U1[n*8+h0], q0); q1 = fmaf(phi, U1[n*8+h1], q1);
    }
    const long o = (((long)v*8 + c)*64 + r)*8;
    p.pkq[o+h0] = k0; p.pkq[o+h1] = k1;
    p.pqq[o+h0] = q0; p.pqq[o+h1] = q1;
}

// ---------------- vo partials: Phi^T @ u2 over an n-chunk of 128 ----------------
__device__ void pvo_dev(int i, const Ptrs& p)
{
    const int tid = threadIdx.x;
    const int v = i >> 3, c = i & 7;
    const int r = tid & 63, hp = tid >> 6;
    const int h0 = hp*2, h1 = h0 + 1;
    float a0 = 0.f, a1 = 0.f;
    const float* Pb = p.Phi + ((long)v*1024 + c*128)*64 + r;
    const float* U2 = p.u2 + ((long)v*1024 + c*128)*8;
    #pragma unroll 4
    for (int n = 0; n < 128; ++n) {
        float phi = Pb[(long)n*64];
        a0 = fmaf(phi, U2[n*8+h0], a0);
        a1 = fmaf(phi, U2[n*8+h1], a1);
    }
    const long o = (((long)v*8 + c)*64 + r)*8;
    p.pvo[o+h0] = a0; p.pvo[o+h1] = a1;
}

// ---------------- consts final (redundant per consumer block) ----------------
__device__ float2 consts_final_dev(char* smem, int v, const Ptrs& p)
{
    const int tid = threadIdx.x;
    const int r = tid & 63, hp = tid >> 6;
    const int h0 = hp*2, h1 = h0 + 1;
    float k0=0.f,k1=0.f,q0=0.f,q1=0.f,w0=0.f,w1=0.f;
    #pragma unroll
    for (int c = 0; c < 8; ++c) {
        const long o = (((long)v*8 + c)*64 + r)*8;
        k0 += p.pkq[o+h0]; k1 += p.pkq[o+h1];
        q0 += p.pqq[o+h0]; q1 += p.pqq[o+h1];
        w0 += p.pvo[o+h0]; w1 += p.pvo[o+h1];
    }
    float bk0=0.f,bk1=0.f,bq0=0.f,bq1=0.f,bv0=0.f,bv1=0.f;
    #pragma unroll 8
    for (int j = 0; j < 64; ++j) {
        float b0 = p.Wk_b[v*512 + h0*64 + j], b1 = p.Wk_b[v*512 + h1*64 + j];
        bk0 = fmaf(b0, p.Wq_w[v*512 + h0*64 + j], bk0);
        bk1 = fmaf(b1, p.Wq_w[v*512 + h1*64 + j], bk1);
        bq0 = fmaf(b0, p.Wq_b[v*512 + h0*64 + j], bq0);
        bq1 = fmaf(b1, p.Wq_b[v*512 + h1*64 + j], bq1);
        float c0v = p.Wv_b[v*512 + h0*64 + j], c1v = p.Wv_b[v*512 + h1*64 + j];
        bv0 = fmaf(c0v, p.opj[v*512 + h0*64 + j], bv0);
        bv1 = fmaf(c1v, p.opj[v*512 + h1*64 + j], bv1);
    }
    w0 += bv0; w1 += bv1;
    k0 += bk0; k1 += bk1; q0 += bq0; q1 += bq1;
    float s1 = k0*w0 + k1*w1;
    float s0 = q0*w0 + q1*w1;
    float sA = p.attn_ob[v*512 + tid]*p.proj_w[v*512 + tid]
             + p.attn_ob[v*512 + 256 + tid]*p.proj_w[v*512 + 256 + tid];
    s1 = wave_sum(s1); s0 = wave_sum(s0); sA = wave_sum(sA);
    float* red = (float*)smem;
    const int w = tid >> 6, l = tid & 63;
    __syncthreads();
    if (l == 0) { red[w] = s1; red[4+w] = s0; red[8+w] = sA; }
    __syncthreads();
    float S1 = red[0]+red[1]+red[2]+red[3];
    float S0 = red[4]+red[5]+red[6]+red[7];
    float SA = red[8]+red[9]+red[10]+red[11];
    __syncthreads();
    const float inv = 0.044194173824159216f;   // 1/sqrt(512)
    float2 res;
    res.x = S1*inv;
    res.y = (S0 + SA)*inv + p.proj_b[v];
    return res;
}

// ---------------- o-GEMM (fp32 B) + fused LN epilogue -> Abig [v*64, v*64+64) ----
__device__ void ogemm_ln_dev(char* smem_, int v, int m0, const Ptrs& p)
{
    const float c1 = consts_final_dev(smem_, v, p).x;  // ends with syncthreads

    ushort_t* lds = (ushort_t*)smem_;
    const int tid = threadIdx.x;
    const int w = tid >> 6, l = tid & 63;
    const int ml = l & 15, kg = l >> 4;
    const int srow = tid >> 2, sslot = tid & 3;
    const int kk = tid >> 3, ng = (tid & 7)*8;
    const ushort_t* A = p.h2_bf + (long)v*262144;
    const float* Bf = p.ffn_w3 + (long)v*32768;    // [512][64]
    const float* bias = p.ffn_b3 + v*64;
    const ushort_t* Ag = A + (long)(m0 + srow)*512 + sslot*8;
    auto L = [&](int buf, int ab, int row, int col) {
        return lds + (((buf*2 + ab)*64 + row)*40 + col);
    };
    auto wrB = [&](int buf, float4 b0, float4 b1) {
        ushort_t* bs = L(buf, 1, 0, 0);
        bs[(ng+0)*40 + kk] = f2bf(b0.x); bs[(ng+1)*40 + kk] = f2bf(b0.y);
        bs[(ng+2)*40 + kk] = f2bf(b0.z); bs[(ng+3)*40 + kk] = f2bf(b0.w);
        bs[(ng+4)*40 + kk] = f2bf(b1.x); bs[(ng+5)*40 + kk] = f2bf(b1.y);
        bs[(ng+6)*40 + kk] = f2bf(b1.z); bs[(ng+7)*40 + kk] = f2bf(b1.w);
    };
    f32x4 acc[4] = {};
    int4 ra = *(const int4*)Ag;
    float4 rb0 = *(const float4*)(Bf + (long)kk*64 + ng);
    float4 rb1 = *(const float4*)(Bf + (long)kk*64 + ng + 4);
    *(int4*)L(0,0,srow,sslot*8) = ra;
    wrB(0, rb0, rb1);
    __syncthreads();
    for (int t = 0; t < 16; ++t) {
        const int cur = t & 1;
        if (t + 1 < 16) {
            ra  = *(const int4*)(Ag + (t+1)*32);
            rb0 = *(const float4*)(Bf + (long)((t+1)*32 + kk)*64 + ng);
            rb1 = *(const float4*)(Bf + (long)((t+1)*32 + kk)*64 + ng + 4);
        }
        short8 af = *(const short8*)L(cur,0,w*16 + ml,kg*8);
        #pragma unroll
        for (int f = 0; f < 4; ++f) {
            short8 bfr = *(const short8*)L(cur,1,f*16 + ml,kg*8);
            acc[f] = __builtin_amdgcn_mfma_f32_16x16x32_bf16(af, bfr, acc[f], 0, 0, 0);
        }
        if (t + 1 < 16) {
            *(int4*)L(cur^1,0,srow,sslot*8) = ra;
            wrB(cur^1, rb0, rb1);
            __syncthreads();
        }
    }
    __syncthreads();                      // reuse smem for o-tile
    float* ot = (float*)smem_;            // [64][66] fp32
    {
        const int rl = w*16 + kg*4;
        #pragma unroll
        for (int f = 0; f < 4; ++f) {
            const int n = ml + f*16;
            const float bs = bias[n];
            #pragma unroll
            for (int r = 0; r < 4; ++r)
                ot[(rl + r)*66 + n] = acc[f][r] + bs;
        }
    }
    __syncthreads();
    const float g  = p.ffn_ln_g[v*64 + l];
    const float bt = p.ffn_ln_b[v*64 + l];
    const float al = p.alpha[v];
    for (int rr = 0; rr < 16; ++rr) {
        const int row = w*16 + rr;
        const int b = m0 + row;
        const float am = bf2f(p.amap_bf[((long)v*512 + b)*64 + l]);
        float t = ot[row*66 + l] + am;
        float mu = wave_sum(t) * (1.0f/64.0f);
        float dd = t - mu;
        float var = wave_sum(dd*dd) * (1.0f/64.0f);
        float u = dd * rsqrtf(var + 1e-5f) * g + bt;
        p.Abig[(long)b*384 + v*64 + l] = f2bf(am*(1.0f + c1) + al*u);
    }
}

// ---------------- bias2: once, 1 block ----------------
__device__ void bias2_dev(char* smem, const Ptrs& p)
{
    const float c00 = consts_final_dev(smem, 0, p).y;
    const float c01 = consts_final_dev(smem, 1, p).y;
    #pragma unroll
    for (int k = 0; k < 8; ++k) {
        const int n2 = k*256 + threadIdx.x;
        const float c0 = (n2 >> 10) ? c01 : c00;
        p.bias2[n2] = p.fu_b4[n2] + c0*p.phirs[n2];
    }
}

// ================= stage kernels =================
__global__ __launch_bounds__(256) void stage0_k(Ptrs p, CvtArgs ca, int ncvt)
{
    extern __shared__ char smem[];
    const int bx = blockIdx.x;
    if (bx < ncvt) {
        int e = 0;
        while (bx >= ca.cum[e+1]) ++e;
        cvt_dev(bx - ca.cum[e], ca.d[e], p);
    } else if (bx < ncvt + 512) {
        control_dev(smem, bx - ncvt, p);
    } else if (bx < ncvt + 768) {
        int i = bx - ncvt - 512;
        a_map_dev(smem, i & 127, i >> 7, p);
    } else if (bx < ncvt + 784) {
        opj_dev(bx - ncvt - 768, p);
    } else {
        u01_dev(bx - ncvt - 784, p);            // 32 blocks
    }
}

__global__ __launch_bounds__(256) void stage1_k(Ptrs p)
{
    extern __shared__ char smem[];
    const int bx = blockIdx.x;
    if (bx < 32) {                              // fu1: M=512,N=256,K=384
        bgemm_f32b_dev(smem, p.fbuf_bf, p.fu_w1, p.fu_b1, p.hA_bf,
                       (bx>>2)*64, (bx&3)*64, 384, 256, 256, 1, true);
    } else if (bx < 160) {                      // ffn1: per-v M=512,N=512,K=64
        int i = bx - 32; int v = i >> 6; i &= 63;
        bgemm_f32b_dev(smem, p.amap_bf + (long)v*32768, p.ffn_w1 + (long)v*32768,
                       p.ffn_b1 + v*512, (void*)(p.h1_bf + (long)v*262144),
                       (i>>3)*64, (i&7)*64, 64, 512, 512, 1, true);
    } else if (bx < 192) {
        u2_dev(bx - 160, p);                    // 32 blocks
    } else {
        kqqq_dev(bx - 192, p);                  // 16 blocks
    }
}

__global__ __launch_bounds__(256) void stage2_k(Ptrs p)
{
    extern __shared__ char smem[];
    const int bx = blockIdx.x;
    if (bx < 64) {                              // fu2: M=512,N=512,K=256
        bgemm_f32b_dev(smem, p.hA_bf, p.fu_w2, p.fu_b2, p.hB_bf,
                       (bx>>3)*64, (bx&7)*64, 256, 512, 512, 1, true);
    } else if (bx < 192) {                      // ffn2: per-v M=512,N=512,K=512
        int i = bx - 64; int v = i >> 6; i &= 63;
        bgemm_f32b_dev(smem, p.h1_bf + (long)v*262144, p.ffn_w2 + (long)v*262144,
                       p.ffn_b2 + v*512, (void*)(p.h2_bf + (long)v*262144),
                       (i>>3)*64, (i&7)*64, 512, 512, 512, 1, true);
    } else {
        pvo_dev(bx - 192, p);                   // 16 blocks
    }
}

__global__ __launch_bounds__(256) void stage3_k(Ptrs p)
{
    extern __shared__ char smem[];
    const int bx = blockIdx.x;
    if (bx < 32) {                              // fu3 -> Abig cols [128:384)
        bgemm_f32b_dev(smem, p.hB_bf, p.fu_w3, p.fu_b3, (void*)(p.Abig + 128),
                       (bx>>2)*64, (bx&3)*64, 512, 256, 384, 1, true);
    } else if (bx < 48) {                       // o-GEMM + LN -> Abig [0:128)
        int i = bx - 32;
        ogemm_ln_dev(smem, i >> 3, (i & 7)*64, p);
    } else {
        bias2_dev(smem, p);                     // 1 block
    }
}

// stage4: out = Abig @ [Bphi | fu_w4^T]^T + bias2. K=384, mixed B staging.
__global__ __launch_bounds__(256) void stage4_k(Ptrs p)
{
    extern __shared__ char smem[];
    ushort_t* lds = (ushort_t*)smem;
    const int bx = blockIdx.x;
    const int m0 = (bx >> 5)*64, n0 = (bx & 31)*64;
    const int tid = threadIdx.x;
    const int w = tid >> 6, l = tid & 63;
    const int ml = l & 15, kg = l >> 4;
    const int srow = tid >> 2, sslot = tid & 3;
    const int kk = tid >> 3, ng = (tid & 7)*8;
    const ushort_t* Ag = p.Abig + (long)(m0 + srow)*384 + sslot*8;
    const ushort_t* Bp = p.Bphi + (long)(n0 + srow)*128 + sslot*8;  // [2048][128]
    const float* Wf = p.fu_w4 + n0 + ng;                             // [256][2048]
    auto L = [&](int buf, int ab, int row, int col) {
        return lds + (((buf*2 + ab)*64 + row)*40 + col);
    };
    auto wrB = [&](int buf, float4 b0, float4 b1) {
        ushort_t* bs = L(buf, 1, 0, 0);
        bs[(ng+0)*40 + kk] = f2bf(b0.x); bs[(ng+1)*40 + kk] = f2bf(b0.y);
        bs[(ng+2)*40 + kk] = f2bf(b0.z); bs[(ng+3)*40 + kk] = f2bf(b0.w);
        bs[(ng+4)*40 + kk] = f2bf(b1.x); bs[(ng+5)*40 + kk] = f2bf(b1.y);
        bs[(ng+6)*40 + kk] = f2bf(b1.z); bs[(ng+7)*40 + kk] = f2bf(b1.w);
    };
    f32x4 acc[4] = {};
    int4 ra = *(const int4*)Ag;
    int4 rbi = *(const int4*)Bp;                 // t=0 (phi region)
    float4 rb0, rb1;
    *(int4*)L(0,0,srow,sslot*8) = ra;
    *(int4*)L(0,1,srow,sslot*8) = rbi;
    __syncthreads();
    for (int t = 0; t < 12; ++t) {
        const int cur = t & 1;
        if (t + 1 < 12) {
            ra = *(const int4*)(Ag + (t+1)*32);
            if (t + 1 < 4) {
                rbi = *(const int4*)(Bp + (t+1)*32);
            } else {
                rb0 = *(const float4*)(Wf + (long)((t+1)*32 - 128 + kk)*2048);
                rb1 = *(const float4*)(Wf + (long)((t+1)*32 - 128 + kk)*2048 + 4);
            }
        }
        short8 af = *(const short8*)L(cur,0,w*16 + ml,kg*8);
        #pragma unroll
        for (int f = 0; f < 4; ++f) {
            short8 bfr = *(const short8*)L(cur,1,f*16 + ml,kg*8);
            acc[f] = __builtin_amdgcn_mfma_f32_16x16x32_bf16(af, bfr, acc[f], 0, 0, 0);
        }
        if (t + 1 < 12) {
            *(int4*)L(cur^1,0,srow,sslot*8) = ra;
            if (t + 1 < 4) *(int4*)L(cur^1,1,srow,sslot*8) = rbi;
            else           wrB(cur^1, rb0, rb1);
            __syncthreads();
        }
    }
    const int mr = m0 + w*16 + kg*4;
    const int nc = n0 + ml;
    #pragma unroll
    for (int f = 0; f < 4; ++f) {
        const int n = nc + f*16;
        const float bs = p.bias2[n];
        #pragma unroll
        for (int r = 0; r < 4; ++r)
            p.out[(long)(mr + r)*2048 + n] = acc[f][r] + bs;
    }
}

extern "C" void kernel_launch(void* const* d_in, const int* in_sizes, int n_in,
                              void* d_out, int out_size, void* d_ws, size_t ws_size,
                              hipStream_t stream)
{
    const float* a_n      = (const float*)d_in[0];
    const float* BC       = (const float*)d_in[1];
    const float* Phi      = (const float*)d_in[2];
    const float* Wq_w     = (const float*)d_in[3];
    const float* Wq_b     = (const float*)d_in[4];
    const float* Wk_w     = (const float*)d_in[5];
    const float* Wk_b     = (const float*)d_in[6];
    const float* Wv_w     = (const float*)d_in[7];
    const float* Wv_b     = (const float*)d_in[8];
    const float* attn_ow  = (const float*)d_in[9];
    const float* attn_ob  = (const float*)d_in[10];
    const float* proj_w   = (const float*)d_in[11];
    const float* proj_b   = (const float*)d_in[12];
    const float* ffn_w1   = (const float*)d_in[13];
    const float* ffn_b1   = (const float*)d_in[14];
    const float* ffn_w2   = (const float*)d_in[15];
    const float* ffn_b2   = (const float*)d_in[16];
    const float* ffn_w3   = (const float*)d_in[17];
    const float* ffn_b3   = (const float*)d_in[18];
    const float* ffn_ln_g = (const float*)d_in[19];
    const float* ffn_ln_b = (const float*)d_in[20];
    const float* a0_w     = (const float*)d_in[21];
    const float* a0_b     = (const float*)d_in[22];
    const float* a0_ln_g  = (const float*)d_in[23];
    const float* a0_ln_b  = (const float*)d_in[24];
    const float* alpha    = (const float*)d_in[25];
    const float* sb_w     = (const float*)d_in[26];
    const float* sb_b     = (const float*)d_in[27];
    const float* cm_w1    = (const float*)d_in[28];
    const float* cm_b1    = (const float*)d_in[29];
    const float* cm_w2    = (const float*)d_in[30];
    const float* cm_b2    = (const float*)d_in[31];
    const float* fu_w1    = (const float*)d_in[32];
    const float* fu_b1    = (const float*)d_in[33];
    const float* fu_w2    = (const float*)d_in[34];
    const float* fu_b2    = (const float*)d_in[35];
    const float* fu_w3    = (const float*)d_in[36];
    const float* fu_b3    = (const float*)d_in[37];
    const float* fu_w4    = (const float*)d_in[38];
    const float* fu_b4    = (const float*)d_in[39];

    float* ws = (float*)d_ws;
    Ptrs p;
    p.a_n = a_n; p.BC = BC; p.Phi = Phi; p.Wq_w = Wq_w; p.Wq_b = Wq_b;
    p.Wk_w = Wk_w; p.Wk_b = Wk_b; p.Wv_w = Wv_w; p.Wv_b = Wv_b;
    p.attn_ow = attn_ow; p.attn_ob = attn_ob; p.proj_w = proj_w; p.proj_b = proj_b;
    p.ffn_w1 = ffn_w1; p.ffn_w2 = ffn_w2; p.ffn_w3 = ffn_w3; p.ffn_b3 = ffn_b3;
    p.ffn_ln_g = ffn_ln_g; p.ffn_ln_b = ffn_ln_b;
    p.a0_w = a0_w; p.a0_b = a0_b; p.a0_ln_g = a0_ln_g; p.a0_ln_b = a0_ln_b;
    p.alpha = alpha; p.sb_w = sb_w; p.sb_b = sb_b;
    p.cm_w1 = cm_w1; p.cm_b1 = cm_b1; p.cm_w2 = cm_w2; p.cm_b2 = cm_b2;
    p.fu_w1 = fu_w1; p.fu_w2 = fu_w2; p.fu_w3 = fu_w3; p.fu_w4 = fu_w4;
    p.fu_b1 = fu_b1; p.fu_b2 = fu_b2; p.fu_b3 = fu_b3; p.fu_b4 = fu_b4;
    p.ffn_b1 = ffn_b1; p.ffn_b2 = ffn_b2;

    p.opj     = ws;                              // 1024
    p.u0      = ws + 1024;                       // 16384 [v][1024][8]
    p.u1      = ws + 17408;                      // 16384
    p.u2      = ws + 33792;                      // 16384
    p.pkq     = ws + 50176;                      // 8192 [v][8][64][8]
    p.pqq     = ws + 58368;                      // 8192
    p.pvo     = ws + 66560;                      // 8192
    p.phirs   = ws + 74752;                      // 2048
    p.bias2   = ws + 76800;                      // 2048
    p.amap_bf = (ushort_t*)(ws + 78848);         // 65536 ush
    p.h1_bf   = (ushort_t*)(ws + 111616);        // 524288 ush
    p.h2_bf   = (ushort_t*)(ws + 373760);        // 524288 ush
    p.fbuf_bf = (ushort_t*)(ws + 635904);        // 196608 ush
    p.hA_bf   = (ushort_t*)(ws + 734208);        // 131072 ush
    p.hB_bf   = (ushort_t*)(ws + 799744);        // 262144 ush
    p.Abig    = (ushort_t*)(ws + 930816);        // 196608 ush [512][384]
    p.Bphi    = (ushort_t*)(ws + 1029120);       // 262144 ush [2048][128]
    p.out     = (float*)d_out;

    CvtArgs ca;
    // v=0: Phi rows -> Bphi[0:1024), live cols 0:64, zero cols 64:128; phirs[0:1024)
    ca.d[0].src = Phi;          ca.d[0].dst = p.Bphi;
    ca.d[0].K = 0;    ca.d[0].ldd = 128; ca.d[0].coff = 0;
    // v=1: Phi rows -> Bphi[1024:2048), live cols 64:128, zero cols 0:64; phirs[1024:2048)
    ca.d[1].src = Phi + 65536;  ca.d[1].dst = p.Bphi + (long)1024*128;
    ca.d[1].K = 1024; ca.d[1].ldd = 128; ca.d[1].coff = 64;
    ca.cum[0] = 0; ca.cum[1] = 16; ca.cum[2] = 32;
    const int ncvt = 32;

    stage0_k<<<ncvt + 816, 256, 4352,  stream>>>(p, ca, ncvt);
    stage1_k<<<208,        256, 20480, stream>>>(p);
    stage2_k<<<208,        256, 20480, stream>>>(p);
    stage3_k<<<49,         256, 20480, stream>>>(p);
    stage4_k<<<256,        256, 20480, stream>>>(p);
}

// Round 12
// 69.651 us; speedup vs baseline: 1.1536x; 1.1536x over previous
//
#include <hip/hip_runtime.h>
#include <hip/hip_bf16.h>
#include <math.h>

// Shapes (fixed): B=512, V=2, NX=1024, R=64, D=512, H=8, S=4, NC=2, HS=64, FIN=384

typedef unsigned short ushort_t;
using short8 = __attribute__((ext_vector_type(8))) short;
using f32x4  = __attribute__((ext_vector_type(4))) float;

__device__ __forceinline__ float gelu_f(float x) {
    float x3 = x*x*x;
    return 0.5f*x*(1.0f + tanhf(0.7978845608028654f*(x + 0.044715f*x3)));
}

__device__ __forceinline__ float wave_sum(float x) {
    #pragma unroll
    for (int m = 32; m >= 1; m >>= 1) x += __shfl_xor(x, m, 64);
    return x;
}

__device__ __forceinline__ ushort_t f2bf(float x) {
    unsigned u = __float_as_uint(x);
    unsigned r = (u + 0x7FFFu + ((u >> 16) & 1u)) >> 16;   // RNE
    return (ushort_t)r;
}
__device__ __forceinline__ float bf2f(ushort_t h) {
    return __uint_as_float(((unsigned)h) << 16);
}

// ---------------- pointer bundle ----------------
struct Ptrs {
    const float *a_n, *BC, *Phi, *Wq_w, *Wq_b, *Wk_w, *Wk_b, *Wv_w, *Wv_b,
                *attn_ow, *attn_ob, *proj_w, *proj_b,
                *ffn_w3, *ffn_b3, *ffn_ln_g, *ffn_ln_b,
                *a0_w, *a0_b, *a0_ln_g, *a0_ln_b, *alpha,
                *sb_w, *sb_b, *cm_w1, *cm_b1, *cm_w2, *cm_b2,
                *fu_b1, *fu_b2, *fu_b3, *fu_b4, *ffn_b1, *ffn_b2;
    float *opj, *u0, *u1, *u2, *pkq, *pqq, *pvo, *phirs, *bias2, *parts,
          *obuf, *out;
    ushort_t *amap_bf, *h1_bf, *h2_bf, *fbuf_bf, *hA_bf, *hB_bf;
    ushort_t *w_fu1t, *w_fu2t, *w_fu3t, *w_ffn1t, *w_ffn2t, *w_ffn3t,
             *Abig, *Bbig;
};

// ---------------- cvt descriptors ----------------
// mode 0: transpose fp32 [K][N] 64x64 tiles -> bf16 [N][ldd] at col offset coff
// mode 2: Phi rows -> Bbig slab (+zero other slab) + phirs rowsums; K = phirs base
struct CvtDesc { const float* src; ushort_t* dst; int K, N, mode, ldd, coff; };
struct CvtArgs { CvtDesc d[12]; int cum[13]; };

__device__ void cvt_dev(char* smem, int tile, const CvtDesc& d, const Ptrs& p)
{
    const int t = threadIdx.x;
    if (d.mode == 2) {
        const int row = t >> 2, q = t & 3;          // 64 rows/block, 4 thr/row
        const float* s = d.src + (long)(tile*64 + row)*64 + q*16;
        ushort_t* dst  = d.dst + (long)(tile*64 + row)*384 + d.coff + q*16;
        ushort_t* dz   = d.dst + (long)(tile*64 + row)*384 + (64 - d.coff) + q*16;
        float sum = 0.f;
        #pragma unroll
        for (int i = 0; i < 4; ++i) {
            float4 x = *(const float4*)(s + i*4);
            ushort4 w; w.x=f2bf(x.x); w.y=f2bf(x.y); w.z=f2bf(x.z); w.w=f2bf(x.w);
            *(ushort4*)(dst + i*4) = w;
            ushort4 z; z.x=0; z.y=0; z.z=0; z.w=0;
            *(ushort4*)(dz + i*4) = z;
            sum += x.x + x.y + x.z + x.w;
        }
        sum += __shfl_xor(sum, 1, 64);
        sum += __shfl_xor(sum, 2, 64);
        if (q == 0) p.phirs[d.K + tile*64 + row] = sum;
    } else {
        // 64x64 fp32 transpose tile -> bf16 [N][ldd]
        float* tl = (float*)smem;                   // [64][65]
        const int ntn = d.N >> 6;
        const int kt = tile / ntn, nt = tile % ntn;
        const int r = t >> 2, c0 = (t & 3) * 16;
        #pragma unroll
        for (int i = 0; i < 4; ++i) {
            float4 v = *(const float4*)(d.src + (long)(kt*64 + r)*d.N + nt*64 + c0 + i*4);
            tl[r*65 + c0 + i*4 + 0] = v.x;
            tl[r*65 + c0 + i*4 + 1] = v.y;
            tl[r*65 + c0 + i*4 + 2] = v.z;
            tl[r*65 + c0 + i*4 + 3] = v.w;
        }
        __syncthreads();
        #pragma unroll
        for (int i = 0; i < 4; ++i) {
            ushort4 w;
            w.x = f2bf(tl[(c0 + i*4 + 0)*65 + r]);
            w.y = f2bf(tl[(c0 + i*4 + 1)*65 + r]);
            w.z = f2bf(tl[(c0 + i*4 + 2)*65 + r]);
            w.w = f2bf(tl[(c0 + i*4 + 3)*65 + r]);
            *(ushort4*)(d.dst + (long)(nt*64 + r)*d.ldd + d.coff + kt*64 + c0 + i*4) = w;
        }
    }
}

// ---------------- bf16 MFMA GEMM (device) ----------------
// EPI: 0 = +bias, 1 = gelu(+bias). OUTBF: bf16 out else fp32.
__device__ void bgemm_dev(char* smem_,
    const ushort_t* __restrict__ A, const ushort_t* __restrict__ B,
    const float* __restrict__ bias,
    void* __restrict__ Cv, int m0, int n0, int K, int ldc,
    int EPI, bool OUTBF)
{
    ushort_t* lds = (ushort_t*)smem_;   // [2][2][64][40]
    const int tid = threadIdx.x;
    const int w = tid >> 6, l = tid & 63;
    const int ml = l & 15, kg = l >> 4;
    const int srow = tid >> 2, sslot = tid & 3;
    const ushort_t* Ag = A + (long)(m0 + srow)*K + sslot*8;
    const ushort_t* Bg = B + (long)(n0 + srow)*K + sslot*8;
    auto L = [&](int buf, int ab, int row, int col) {
        return lds + (((buf*2 + ab)*64 + row)*40 + col);
    };
    f32x4 acc[4] = {};
    const int nt = K >> 5;
    int4 ra = *(const int4*)Ag;
    int4 rb = *(const int4*)Bg;
    *(int4*)L(0,0,srow,sslot*8) = ra;
    *(int4*)L(0,1,srow,sslot*8) = rb;
    __syncthreads();
    for (int t = 0; t < nt; ++t) {
        const int cur = t & 1;
        if (t + 1 < nt) {
            ra = *(const int4*)(Ag + (t+1)*32);
            rb = *(const int4*)(Bg + (t+1)*32);
        }
        short8 af = *(const short8*)L(cur,0,w*16 + ml,kg*8);
        #pragma unroll
        for (int f = 0; f < 4; ++f) {
            short8 bfr = *(const short8*)L(cur,1,f*16 + ml,kg*8);
            acc[f] = __builtin_amdgcn_mfma_f32_16x16x32_bf16(af, bfr, acc[f], 0, 0, 0);
        }
        if (t + 1 < nt) {
            *(int4*)L(cur^1,0,srow,sslot*8) = ra;
            *(int4*)L(cur^1,1,srow,sslot*8) = rb;
            __syncthreads();
        }
    }
    float* Cf = (float*)Cv; ushort_t* Cb = (ushort_t*)Cv;
    const int mr = m0 + w*16 + kg*4;
    const int nc = n0 + ml;
    #pragma unroll
    for (int f = 0; f < 4; ++f) {
        const int n = nc + f*16;
        const float bs = bias[n];
        #pragma unroll
        for (int r = 0; r < 4; ++r) {
            float x = acc[f][r] + bs;
            if (EPI == 1) x = gelu_f(x);
            if (OUTBF) Cb[(long)(mr + r)*ldc + n] = f2bf(x);
            else       Cf[(long)(mr + r)*ldc + n] = x;
        }
    }
}

// ---------------- control: f = [sf(256), cf(128)] bf16 ----------------
__device__ void control_dev(char* smem, int b, const Ptrs& p)
{
    float* bc  = (float*)smem;        // 8
    float* cf1 = bc + 8;              // 64
    const int tid = threadIdx.x;
    if (tid < 6) bc[tid] = p.BC[b*6 + tid];
    __syncthreads();
    {
        int s = tid >> 6;
        p.fbuf_bf[(long)b*384 + tid] = f2bf(gelu_f(bc[s]*p.sb_w[tid] + p.sb_b[tid]));
    }
    if (tid < 64) {
        cf1[tid] = gelu_f(bc[4]*p.cm_w1[tid] + bc[5]*p.cm_w1[64+tid] + p.cm_b1[tid]);
    }
    __syncthreads();
    if (tid < 128) {
        float acc = p.cm_b2[tid];
        #pragma unroll 8
        for (int i = 0; i < 64; ++i) acc = fmaf(cf1[i], p.cm_w2[i*128 + tid], acc);
        p.fbuf_bf[(long)b*384 + 256 + tid] = f2bf(gelu_f(acc));
    }
}

// ---------------- a_map = LN(relu(a_n @ a0_w + a0_b)) bf16 ----------------
__device__ void a_map_dev(char* smem, int bx, int v, const Ptrs& p)
{
    float* arow = (float*)smem;       // [4][64]
    const int w = threadIdx.x >> 6, lane = threadIdx.x & 63;
    const int b = bx*4 + w;
    arow[w*64 + lane] = p.a_n[((long)b*2 + v)*64 + lane];
    __syncthreads();
    float acc = p.a0_b[v*64 + lane];
    #pragma unroll 8
    for (int rp = 0; rp < 64; ++rp)
        acc = fmaf(arow[w*64 + rp], p.a0_w[((long)v*64 + rp)*64 + lane], acc);
    float x = fmaxf(acc, 0.0f);
    float mu = wave_sum(x) * (1.0f/64.0f);
    float d = x - mu;
    float var = wave_sum(d*d) * (1.0f/64.0f);
    float y = d * rsqrtf(var + 1e-5f) * p.a0_ln_g[v*64 + lane] + p.a0_ln_b[v*64 + lane];
    p.amap_bf[((long)v*512 + b)*64 + lane] = f2bf(y);
}

// ---------------- opj[v,d] = sum_e attn_ow[v,d,e]*proj_w[v,e] ----------------
__device__ void opj_dev(int oi, const Ptrs& p)
{
    const int tid = threadIdx.x;
    const int v = oi >> 3, dc = oi & 7;
    const int d = dc*64 + (tid >> 2);
    const int e0 = (tid & 3)*128;
    const float* row = p.attn_ow + ((long)v*512 + d)*512 + e0;
    const float* pj  = p.proj_w + v*512 + e0;
    float s = 0.f;
    #pragma unroll 8
    for (int j = 0; j < 128; ++j) s = fmaf(row[j], pj[j], s);
    s += __shfl_xor(s, 1, 64);
    s += __shfl_xor(s, 2, 64);
    if ((tid & 3) == 0) p.opj[v*512 + d] = s;
}

// ---------------- u0/u1: per-head matvecs of Wk against Wq_w / Wq_b ----------------
__device__ void u01_dev(int i, const Ptrs& p)
{
    const int tid = threadIdx.x;
    const int w = tid >> 6, lane = tid & 63;
    const int v = i >> 4, c = i & 15;            // 64-row chunk
    const float* wq = p.Wq_w + v*512;
    const float* wb = p.Wq_b + v*512;
    for (int pass = 0; pass < 16; ++pass) {
        const int n = c*64 + pass*4 + w;
        const float* row = p.Wk_w + ((long)v*1024 + n)*512 + lane*8;
        float4 a = *(const float4*)row, b = *(const float4*)(row + 4);
        float s0 = 0.f, s1 = 0.f;
        #pragma unroll
        for (int j = 0; j < 8; ++j) {
            float x = (j < 4) ? ((const float*)&a)[j] : ((const float*)&b)[j-4];
            s0 = fmaf(x, wq[lane*8 + j], s0);
            s1 = fmaf(x, wb[lane*8 + j], s1);
        }
        s0 += __shfl_xor(s0,1,64); s0 += __shfl_xor(s0,2,64); s0 += __shfl_xor(s0,4,64);
        s1 += __shfl_xor(s1,1,64); s1 += __shfl_xor(s1,2,64); s1 += __shfl_xor(s1,4,64);
        if ((lane & 7) == 0) {
            const int h = lane >> 3;
            p.u0[((long)v*1024 + n)*8 + h] = s0;
            p.u1[((long)v*1024 + n)*8 + h] = s1;
        }
    }
}

// ---------------- u2: per-head matvec of Wv against opj ----------------
__device__ void u2_dev(int i, const Ptrs& p)
{
    const int tid = threadIdx.x;
    const int w = tid >> 6, lane = tid & 63;
    const int v = i >> 4, c = i & 15;
    const float* oj = p.opj + v*512;
    for (int pass = 0; pass < 16; ++pass) {
        const int n = c*64 + pass*4 + w;
        const float* row = p.Wv_w + ((long)v*1024 + n)*512 + lane*8;
        float4 a = *(const float4*)row, b = *(const float4*)(row + 4);
        float s0 = 0.f;
        #pragma unroll
        for (int j = 0; j < 8; ++j) {
            float x = (j < 4) ? ((const float*)&a)[j] : ((const float*)&b)[j-4];
            s0 = fmaf(x, oj[lane*8 + j], s0);
        }
        s0 += __shfl_xor(s0,1,64); s0 += __shfl_xor(s0,2,64); s0 += __shfl_xor(s0,4,64);
        if ((lane & 7) == 0) p.u2[((long)v*1024 + n)*8 + (lane >> 3)] = s0;
    }
}

// ---------------- kq/qq partials: Phi^T @ u0/u1 over an n-chunk of 128 ----------------
__device__ void kqqq_dev(int i, const Ptrs& p)
{
    const int tid = threadIdx.x;
    const int v = i >> 3, c = i & 7;
    const int r = tid & 63, hp = tid >> 6;
    const int h0 = hp*2, h1 = h0 + 1;
    float k0=0.f,k1=0.f,q0=0.f,q1=0.f;
    const float* Pb = p.Phi + ((long)v*1024 + c*128)*64 + r;
    const float* U0 = p.u0 + ((long)v*1024 + c*128)*8;
    const float* U1 = p.u1 + ((long)v*1024 + c*128)*8;
    #pragma unroll 4
    for (int n = 0; n < 128; ++n) {
        float phi = Pb[(long)n*64];
        k0 = fmaf(phi, U0[n*8+h0], k0); k1 = fmaf(phi, U0[n*8+h1], k1);
        q0 = fmaf(phi, U1[n*8+h0], q0); q1 = fmaf(phi, U1[n*8+h1], q1);
    }
    const long o = (((long)v*8 + c)*64 + r)*8;
    p.pkq[o+h0] = k0; p.pkq[o+h1] = k1;
    p.pqq[o+h0] = q0; p.pqq[o+h1] = q1;
}

// ---------------- vo partials: Phi^T @ u2 over an n-chunk of 128 ----------------
__device__ void pvo_dev(int i, const Ptrs& p)
{
    const int tid = threadIdx.x;
    const int v = i >> 3, c = i & 7;
    const int r = tid & 63, hp = tid >> 6;
    const int h0 = hp*2, h1 = h0 + 1;
    float a0 = 0.f, a1 = 0.f;
    const float* Pb = p.Phi + ((long)v*1024 + c*128)*64 + r;
    const float* U2 = p.u2 + ((long)v*1024 + c*128)*8;
    #pragma unroll 4
    for (int n = 0; n < 128; ++n) {
        float phi = Pb[(long)n*64];
        a0 = fmaf(phi, U2[n*8+h0], a0);
        a1 = fmaf(phi, U2[n*8+h1], a1);
    }
    const long o = (((long)v*8 + c)*64 + r)*8;
    p.pvo[o+h0] = a0; p.pvo[o+h1] = a1;
}

// ---------------- consts final (run in consumer blocks) ----------------
__device__ float2 consts_final_dev(char* smem, int v, const Ptrs& p)
{
    const int tid = threadIdx.x;
    const int r = tid & 63, hp = tid >> 6;
    const int h0 = hp*2, h1 = h0 + 1;
    float k0=0.f,k1=0.f,q0=0.f,q1=0.f,w0=0.f,w1=0.f;
    #pragma unroll
    for (int c = 0; c < 8; ++c) {
        const long o = (((long)v*8 + c)*64 + r)*8;
        k0 += p.pkq[o+h0]; k1 += p.pkq[o+h1];
        q0 += p.pqq[o+h0]; q1 += p.pqq[o+h1];
        w0 += p.pvo[o+h0]; w1 += p.pvo[o+h1];
    }
    float bk0=0.f,bk1=0.f,bq0=0.f,bq1=0.f,bv0=0.f,bv1=0.f;
    #pragma unroll 8
    for (int j = 0; j < 64; ++j) {
        float b0 = p.Wk_b[v*512 + h0*64 + j], b1 = p.Wk_b[v*512 + h1*64 + j];
        bk0 = fmaf(b0, p.Wq_w[v*512 + h0*64 + j], bk0);
        bk1 = fmaf(b1, p.Wq_w[v*512 + h1*64 + j], bk1);
        bq0 = fmaf(b0, p.Wq_b[v*512 + h0*64 + j], bq0);
        bq1 = fmaf(b1, p.Wq_b[v*512 + h1*64 + j], bq1);
        float c0v = p.Wv_b[v*512 + h0*64 + j], c1v = p.Wv_b[v*512 + h1*64 + j];
        bv0 = fmaf(c0v, p.opj[v*512 + h0*64 + j], bv0);
        bv1 = fmaf(c1v, p.opj[v*512 + h1*64 + j], bv1);
    }
    w0 += bv0; w1 += bv1;
    k0 += bk0; k1 += bk1; q0 += bq0; q1 += bq1;
    float s1 = k0*w0 + k1*w1;
    float s0 = q0*w0 + q1*w1;
    float sA = p.attn_ob[v*512 + tid]*p.proj_w[v*512 + tid]
             + p.attn_ob[v*512 + 256 + tid]*p.proj_w[v*512 + 256 + tid];
    s1 = wave_sum(s1); s0 = wave_sum(s0); sA = wave_sum(sA);
    float* red = (float*)smem;
    const int w = tid >> 6, l = tid & 63;
    __syncthreads();
    if (l == 0) { red[w] = s1; red[4+w] = s0; red[8+w] = sA; }
    __syncthreads();
    float S1 = red[0]+red[1]+red[2]+red[3];
    float S0 = red[4]+red[5]+red[6]+red[7];
    float SA = red[8]+red[9]+red[10]+red[11];
    __syncthreads();
    const float inv = 0.044194173824159216f;   // 1/sqrt(512)
    float2 res;
    res.x = S1*inv;
    res.y = (S0 + SA)*inv + p.proj_b[v];
    return res;
}

// ---------------- bias2 + parts: once, 1 block ----------------
__device__ void bias2_dev(char* smem, const Ptrs& p)
{
    const float2 cv0 = consts_final_dev(smem, 0, p);
    const float2 cv1 = consts_final_dev(smem, 1, p);
    if (threadIdx.x == 0) {
        p.parts[0] = cv0.x; p.parts[1] = cv1.x;
        p.parts[2] = cv0.y; p.parts[3] = cv1.y;
    }
    #pragma unroll
    for (int k = 0; k < 8; ++k) {
        const int n2 = k*256 + threadIdx.x;
        const float c0 = (n2 >> 10) ? cv1.y : cv0.y;
        p.bias2[n2] = p.fu_b4[n2] + c0*p.phirs[n2];
    }
}

// ================= stage kernels =================
__global__ __launch_bounds__(256) void stage0_k(Ptrs p, CvtArgs ca, int ncvt)
{
    extern __shared__ char smem[];
    const int bx = blockIdx.x;
    if (bx < ncvt) {
        int e = 0;
        while (bx >= ca.cum[e+1]) ++e;
        cvt_dev(smem, bx - ca.cum[e], ca.d[e], p);
    } else if (bx < ncvt + 512) {
        control_dev(smem, bx - ncvt, p);
    } else if (bx < ncvt + 768) {
        int i = bx - ncvt - 512;
        a_map_dev(smem, i & 127, i >> 7, p);
    } else if (bx < ncvt + 784) {
        opj_dev(bx - ncvt - 768, p);
    } else {
        u01_dev(bx - ncvt - 784, p);            // 32 blocks
    }
}

__global__ __launch_bounds__(256) void stage1_k(Ptrs p)
{
    extern __shared__ char smem[];
    const int bx = blockIdx.x;
    if (bx < 32) {                              // fu1: M=512,N=256,K=384
        bgemm_dev(smem, p.fbuf_bf, p.w_fu1t, p.fu_b1, p.hA_bf,
                  (bx>>2)*64, (bx&3)*64, 384, 256, 1, true);
    } else if (bx < 160) {                      // ffn1: per-v M=512,N=512,K=64
        int i = bx - 32; int v = i >> 6; i &= 63;
        bgemm_dev(smem, p.amap_bf + (long)v*32768, p.w_ffn1t + (long)v*32768,
                  p.ffn_b1 + v*512, (void*)(p.h1_bf + (long)v*262144),
                  (i>>3)*64, (i&7)*64, 64, 512, 1, true);
    } else if (bx < 192) {
        u2_dev(bx - 160, p);                    // 32 blocks
    } else {
        kqqq_dev(bx - 192, p);                  // 16 blocks
    }
}

__global__ __launch_bounds__(256) void stage2_k(Ptrs p)
{
    extern __shared__ char smem[];
    const int bx = blockIdx.x;
    if (bx < 64) {                              // fu2: M=512,N=512,K=256
        bgemm_dev(smem, p.hA_bf, p.w_fu2t, p.fu_b2, p.hB_bf,
                  (bx>>3)*64, (bx&7)*64, 256, 512, 1, true);
    } else if (bx < 192) {                      // ffn2: per-v M=512,N=512,K=512
        int i = bx - 64; int v = i >> 6; i &= 63;
        bgemm_dev(smem, p.h1_bf + (long)v*262144, p.w_ffn2t + (long)v*262144,
                  p.ffn_b2 + v*512, (void*)(p.h2_bf + (long)v*262144),
                  (i>>3)*64, (i&7)*64, 512, 512, 1, true);
    } else {
        pvo_dev(bx - 192, p);                   // 16 blocks
    }
}

__global__ __launch_bounds__(256) void stage3_k(Ptrs p)
{
    extern __shared__ char smem[];
    const int bx = blockIdx.x;
    if (bx < 32) {                              // fu3 -> Abig cols [128:384)
        bgemm_dev(smem, p.hB_bf, p.w_fu3t, p.fu_b3, (void*)(p.Abig + 128),
                  (bx>>2)*64, (bx&3)*64, 512, 384, 1, true);
    } else if (bx < 48) {                       // o-GEMM: per-v M=512,N=64,K=512
        int i = bx - 32; int v = i >> 3; int m = i & 7;
        bgemm_dev(smem, p.h2_bf + (long)v*262144, p.w_ffn3t + (long)v*32768,
                  p.ffn_b3 + v*64, (void*)(p.obuf + (long)v*32768),
                  m*64, 0, 512, 64, 0, false);
    } else {
        bias2_dev(smem, p);                     // 1 block (also writes parts)
    }
}

// ofuse finish: u = LN(o+amap); Abig[:,v*64+j] = am*(1+c1) + alpha*u
__global__ __launch_bounds__(256) void stage3b_k(Ptrs p)
{
    const int g = blockIdx.x*4 + (threadIdx.x >> 6);   // 1024 wave-rows
    const int lane = threadIdx.x & 63;
    const int v = g >> 9, b = g & 511;
    const float o  = p.obuf[((long)v*512 + b)*64 + lane];
    const float am = bf2f(p.amap_bf[((long)v*512 + b)*64 + lane]);
    float t = o + am;
    float mu = wave_sum(t) * (1.0f/64.0f);
    float dd = t - mu;
    float var = wave_sum(dd*dd) * (1.0f/64.0f);
    float u = dd * rsqrtf(var + 1e-5f) * p.ffn_ln_g[v*64+lane] + p.ffn_ln_b[v*64+lane];
    const float c1 = p.parts[v];
    p.Abig[(long)b*384 + v*64 + lane] = f2bf(am*(1.0f + c1) + p.alpha[v]*u);
}

__global__ __launch_bounds__(256) void stage4_k(Ptrs p)
{
    extern __shared__ char smem[];              // big GEMM M=512,N=2048,K=384
    const int bx = blockIdx.x;
    bgemm_dev(smem, p.Abig, p.Bbig, p.bias2, (void*)p.out,
              (bx>>5)*64, (bx&31)*64, 384, 2048, 0, false);
}

extern "C" void kernel_launch(void* const* d_in, const int* in_sizes, int n_in,
                              void* d_out, int out_size, void* d_ws, size_t ws_size,
                              hipStream_t stream)
{
    const float* a_n      = (const float*)d_in[0];
    const float* BC       = (const float*)d_in[1];
    const float* Phi      = (const float*)d_in[2];
    const float* Wq_w     = (const float*)d_in[3];
    const float* Wq_b     = (const float*)d_in[4];
    const float* Wk_w     = (const float*)d_in[5];
    const float* Wk_b     = (const float*)d_in[6];
    const float* Wv_w     = (const float*)d_in[7];
    const float* Wv_b     = (const float*)d_in[8];
    const float* attn_ow  = (const float*)d_in[9];
    const float* attn_ob  = (const float*)d_in[10];
    const float* proj_w   = (const float*)d_in[11];
    const float* proj_b   = (const float*)d_in[12];
    const float* ffn_w1   = (const float*)d_in[13];
    const float* ffn_b1   = (const float*)d_in[14];
    const float* ffn_w2   = (const float*)d_in[15];
    const float* ffn_b2   = (const float*)d_in[16];
    const float* ffn_w3   = (const float*)d_in[17];
    const float* ffn_b3   = (const float*)d_in[18];
    const float* ffn_ln_g = (const float*)d_in[19];
    const float* ffn_ln_b = (const float*)d_in[20];
    const float* a0_w     = (const float*)d_in[21];
    const float* a0_b     = (const float*)d_in[22];
    const float* a0_ln_g  = (const float*)d_in[23];
    const float* a0_ln_b  = (const float*)d_in[24];
    const float* alpha    = (const float*)d_in[25];
    const float* sb_w     = (const float*)d_in[26];
    const float* sb_b     = (const float*)d_in[27];
    const float* cm_w1    = (const float*)d_in[28];
    const float* cm_b1    = (const float*)d_in[29];
    const float* cm_w2    = (const float*)d_in[30];
    const float* cm_b2    = (const float*)d_in[31];
    const float* fu_w1    = (const float*)d_in[32];
    const float* fu_b1    = (const float*)d_in[33];
    const float* fu_w2    = (const float*)d_in[34];
    const float* fu_b2    = (const float*)d_in[35];
    const float* fu_w3    = (const float*)d_in[36];
    const float* fu_b3    = (const float*)d_in[37];
    const float* fu_w4    = (const float*)d_in[38];
    const float* fu_b4    = (const float*)d_in[39];

    float* ws = (float*)d_ws;
    Ptrs p;
    p.a_n = a_n; p.BC = BC; p.Phi = Phi; p.Wq_w = Wq_w; p.Wq_b = Wq_b;
    p.Wk_w = Wk_w; p.Wk_b = Wk_b; p.Wv_w = Wv_w; p.Wv_b = Wv_b;
    p.attn_ow = attn_ow; p.attn_ob = attn_ob; p.proj_w = proj_w; p.proj_b = proj_b;
    p.ffn_w3 = ffn_w3; p.ffn_b3 = ffn_b3; p.ffn_ln_g = ffn_ln_g; p.ffn_ln_b = ffn_ln_b;
    p.a0_w = a0_w; p.a0_b = a0_b; p.a0_ln_g = a0_ln_g; p.a0_ln_b = a0_ln_b;
    p.alpha = alpha; p.sb_w = sb_w; p.sb_b = sb_b;
    p.cm_w1 = cm_w1; p.cm_b1 = cm_b1; p.cm_w2 = cm_w2; p.cm_b2 = cm_b2;
    p.fu_b1 = fu_b1; p.fu_b2 = fu_b2; p.fu_b3 = fu_b3; p.fu_b4 = fu_b4;
    p.ffn_b1 = ffn_b1; p.ffn_b2 = ffn_b2;

    p.opj     = ws;                              // 1024
    p.u0      = ws + 1024;                       // 16384 [v][1024][8]
    p.u1      = ws + 17408;                      // 16384
    p.u2      = ws + 33792;                      // 16384
    p.pkq     = ws + 50176;                      // 8192 [v][8][64][8]
    p.pqq     = ws + 58368;                      // 8192
    p.pvo     = ws + 66560;                      // 8192
    p.phirs   = ws + 74752;                      // 2048
    p.bias2   = ws + 76800;                      // 2048
    p.parts   = ws + 78848;                      // 128 (4 used)
    p.amap_bf = (ushort_t*)(ws + 78976);         // 65536 ush
    p.h1_bf   = (ushort_t*)(ws + 111744);        // 524288 ush
    p.h2_bf   = (ushort_t*)(ws + 373888);        // 524288 ush
    p.fbuf_bf = (ushort_t*)(ws + 636032);        // 196608 ush
    p.hA_bf   = (ushort_t*)(ws + 734336);        // 131072 ush
    p.hB_bf   = (ushort_t*)(ws + 799872);        // 262144 ush
    p.w_fu1t  = (ushort_t*)(ws + 930944);        // 98304  [256][384]
    p.w_fu2t  = (ushort_t*)(ws + 980096);        // 131072 [512][256]
    p.w_fu3t  = (ushort_t*)(ws + 1045632);       // 131072 [256][512]
    p.w_ffn1t = (ushort_t*)(ws + 1111168);       // 65536  [v][512][64]
    p.w_ffn2t = (ushort_t*)(ws + 1143936);       // 524288 [v][512][512]
    p.w_ffn3t = (ushort_t*)(ws + 1406080);       // 65536  [v][64][512]
    p.Abig    = (ushort_t*)(ws + 1438848);       // 196608 [512][384]
    p.Bbig    = (ushort_t*)(ws + 1537152);       // 786432 [2048][384]
    p.obuf    = ws + 1930368;                    // 65536 fp32 [v][512][64]
    p.out     = (float*)d_out;

    CvtArgs ca;
    auto set = [&](int i, const float* s, ushort_t* dst, int K, int N,
                   int mode, int ldd, int coff) {
        ca.d[i].src = s; ca.d[i].dst = dst; ca.d[i].K = K; ca.d[i].N = N;
        ca.d[i].mode = mode; ca.d[i].ldd = ldd; ca.d[i].coff = coff;
    };
    set(0,  fu_w1,           p.w_fu1t,           384, 256,  0, 384, 0);
    set(1,  fu_w2,           p.w_fu2t,           256, 512,  0, 256, 0);
    set(2,  fu_w3,           p.w_fu3t,           512, 256,  0, 512, 0);
    set(3,  fu_w4,           p.Bbig,             256, 2048, 0, 384, 128);
    set(4,  ffn_w1,          p.w_ffn1t,          64,  512,  0, 64,  0);
    set(5,  ffn_w1 + 32768,  p.w_ffn1t + 32768,  64,  512,  0, 64,  0);
    set(6,  ffn_w2,          p.w_ffn2t,          512, 512,  0, 512, 0);
    set(7,  ffn_w2 + 262144, p.w_ffn2t + 262144, 512, 512,  0, 512, 0);
    set(8,  Phi,             p.Bbig,             0,    0,   2, 384, 0);    // v=0
    set(9,  Phi + 65536,     p.Bbig + (long)1024*384, 1024, 0, 2, 384, 64); // v=1
    set(10, ffn_w3,          p.w_ffn3t,          512, 64,   0, 512, 0);
    set(11, ffn_w3 + 32768,  p.w_ffn3t + 32768,  512, 64,   0, 512, 0);
    // 64x64 tiles for mode 0: (K/64)*(N/64); mode 2 unchanged (16 each)
    const int tl[12] = {24,32,32,128,8,8,64,64,16,16,8,8};
    ca.cum[0] = 0;
    for (int i = 0; i < 12; ++i) ca.cum[i+1] = ca.cum[i] + tl[i];
    const int ncvt = ca.cum[12];                 // 408

    stage0_k <<<ncvt + 816, 256, 16896, stream>>>(p, ca, ncvt);
    stage1_k <<<208,        256, 20480, stream>>>(p);
    stage2_k <<<208,        256, 20480, stream>>>(p);
    stage3_k <<<49,         256, 20480, stream>>>(p);
    stage3b_k<<<256,        256, 0,     stream>>>(p);
    stage4_k <<<256,        256, 20480, stream>>>(p);
}

// Round 13
// 67.969 us; speedup vs baseline: 1.1822x; 1.0248x over previous
//
#include <hip/hip_runtime.h>
#include <hip/hip_bf16.h>
#include <math.h>

// Shapes (fixed): B=512, V=2, NX=1024, R=64, D=512, H=8, S=4, NC=2, HS=64, FIN=384

typedef unsigned short ushort_t;
using short8 = __attribute__((ext_vector_type(8))) short;
using f32x4  = __attribute__((ext_vector_type(4))) float;

__device__ __forceinline__ float gelu_f(float x) {
    float x3 = x*x*x;
    return 0.5f*x*(1.0f + tanhf(0.7978845608028654f*(x + 0.044715f*x3)));
}

__device__ __forceinline__ float wave_sum(float x) {
    #pragma unroll
    for (int m = 32; m >= 1; m >>= 1) x += __shfl_xor(x, m, 64);
    return x;
}

__device__ __forceinline__ ushort_t f2bf(float x) {
    unsigned u = __float_as_uint(x);
    unsigned r = (u + 0x7FFFu + ((u >> 16) & 1u)) >> 16;   // RNE
    return (ushort_t)r;
}
__device__ __forceinline__ float bf2f(ushort_t h) {
    return __uint_as_float(((unsigned)h) << 16);
}

// ---------------- pointer bundle ----------------
struct Ptrs {
    const float *a_n, *BC, *Phi, *Wq_w, *Wq_b, *Wk_w, *Wk_b, *Wv_w, *Wv_b,
                *attn_ow, *attn_ob, *proj_w, *proj_b,
                *ffn_w3, *ffn_b3, *ffn_ln_g, *ffn_ln_b,
                *a0_w, *a0_b, *a0_ln_g, *a0_ln_b, *alpha,
                *sb_w, *sb_b, *cm_w1, *cm_b1, *cm_w2, *cm_b2,
                *fu_b1, *fu_b2, *fu_b3, *fu_b4, *ffn_b1, *ffn_b2;
    float *opj, *u0, *u1, *u2, *pkq, *pqq, *pvo, *phirs, *bias2, *parts,
          *obuf, *out;
    ushort_t *amap_bf, *h1_bf, *h2_bf, *fbuf_bf, *hA_bf, *hB_bf;
    ushort_t *w_fu1t, *w_fu2t, *w_fu3t, *w_ffn1t, *w_ffn2t, *w_ffn3t,
             *Abig, *Bbig;
};

// ---------------- cvt descriptors ----------------
// mode 0: transpose fp32 [K][N] 64x64 tiles -> bf16 [N][ldd] at col offset coff
// mode 2: Phi rows -> Bbig slab (+zero other slab) + phirs rowsums; K = phirs base
struct CvtDesc { const float* src; ushort_t* dst; int K, N, mode, ldd, coff; };
struct CvtArgs { CvtDesc d[12]; int cum[13]; };

__device__ void cvt_tile(char* smem, int gtile, const CvtArgs& ca, const Ptrs& p)
{
    int e = 0;
    while (gtile >= ca.cum[e+1]) ++e;
    const CvtDesc d = ca.d[e];
    const int tile = gtile - ca.cum[e];
    const int t = threadIdx.x;
    if (d.mode == 2) {
        const int row = t >> 2, q = t & 3;          // 64 rows/block, 4 thr/row
        const float* s = d.src + (long)(tile*64 + row)*64 + q*16;
        ushort_t* dst  = d.dst + (long)(tile*64 + row)*384 + d.coff + q*16;
        ushort_t* dz   = d.dst + (long)(tile*64 + row)*384 + (64 - d.coff) + q*16;
        float sum = 0.f;
        #pragma unroll
        for (int i = 0; i < 4; ++i) {
            float4 x = *(const float4*)(s + i*4);
            ushort4 w; w.x=f2bf(x.x); w.y=f2bf(x.y); w.z=f2bf(x.z); w.w=f2bf(x.w);
            *(ushort4*)(dst + i*4) = w;
            ushort4 z; z.x=0; z.y=0; z.z=0; z.w=0;
            *(ushort4*)(dz + i*4) = z;
            sum += x.x + x.y + x.z + x.w;
        }
        sum += __shfl_xor(sum, 1, 64);
        sum += __shfl_xor(sum, 2, 64);
        if (q == 0) p.phirs[d.K + tile*64 + row] = sum;
    } else {
        // 64x64 fp32 transpose tile -> bf16 [N][ldd]
        float* tl = (float*)smem;                   // [64][65]
        const int ntn = d.N >> 6;
        const int kt = tile / ntn, nt = tile % ntn;
        const int r = t >> 2, c0 = (t & 3) * 16;
        #pragma unroll
        for (int i = 0; i < 4; ++i) {
            float4 v = *(const float4*)(d.src + (long)(kt*64 + r)*d.N + nt*64 + c0 + i*4);
            tl[r*65 + c0 + i*4 + 0] = v.x;
            tl[r*65 + c0 + i*4 + 1] = v.y;
            tl[r*65 + c0 + i*4 + 2] = v.z;
            tl[r*65 + c0 + i*4 + 3] = v.w;
        }
        __syncthreads();
        #pragma unroll
        for (int i = 0; i < 4; ++i) {
            ushort4 w;
            w.x = f2bf(tl[(c0 + i*4 + 0)*65 + r]);
            w.y = f2bf(tl[(c0 + i*4 + 1)*65 + r]);
            w.z = f2bf(tl[(c0 + i*4 + 2)*65 + r]);
            w.w = f2bf(tl[(c0 + i*4 + 3)*65 + r]);
            *(ushort4*)(d.dst + (long)(nt*64 + r)*d.ldd + d.coff + kt*64 + c0 + i*4) = w;
        }
    }
}

// ---------------- bf16 MFMA GEMM (device) ----------------
// EPI: 0 = +bias, 1 = gelu(+bias). OUTBF: bf16 out else fp32.
__device__ void bgemm_dev(char* smem_,
    const ushort_t* __restrict__ A, const ushort_t* __restrict__ B,
    const float* __restrict__ bias,
    void* __restrict__ Cv, int m0, int n0, int K, int ldc,
    int EPI, bool OUTBF)
{
    ushort_t* lds = (ushort_t*)smem_;   // [2][2][64][40]
    const int tid = threadIdx.x;
    const int w = tid >> 6, l = tid & 63;
    const int ml = l & 15, kg = l >> 4;
    const int srow = tid >> 2, sslot = tid & 3;
    const ushort_t* Ag = A + (long)(m0 + srow)*K + sslot*8;
    const ushort_t* Bg = B + (long)(n0 + srow)*K + sslot*8;
    auto L = [&](int buf, int ab, int row, int col) {
        return lds + (((buf*2 + ab)*64 + row)*40 + col);
    };
    f32x4 acc[4] = {};
    const int nt = K >> 5;
    int4 ra = *(const int4*)Ag;
    int4 rb = *(const int4*)Bg;
    *(int4*)L(0,0,srow,sslot*8) = ra;
    *(int4*)L(0,1,srow,sslot*8) = rb;
    __syncthreads();
    for (int t = 0; t < nt; ++t) {
        const int cur = t & 1;
        if (t + 1 < nt) {
            ra = *(const int4*)(Ag + (t+1)*32);
            rb = *(const int4*)(Bg + (t+1)*32);
        }
        short8 af = *(const short8*)L(cur,0,w*16 + ml,kg*8);
        #pragma unroll
        for (int f = 0; f < 4; ++f) {
            short8 bfr = *(const short8*)L(cur,1,f*16 + ml,kg*8);
            acc[f] = __builtin_amdgcn_mfma_f32_16x16x32_bf16(af, bfr, acc[f], 0, 0, 0);
        }
        if (t + 1 < nt) {
            *(int4*)L(cur^1,0,srow,sslot*8) = ra;
            *(int4*)L(cur^1,1,srow,sslot*8) = rb;
            __syncthreads();
        }
    }
    float* Cf = (float*)Cv; ushort_t* Cb = (ushort_t*)Cv;
    const int mr = m0 + w*16 + kg*4;
    const int nc = n0 + ml;
    #pragma unroll
    for (int f = 0; f < 4; ++f) {
        const int n = nc + f*16;
        const float bs = bias[n];
        #pragma unroll
        for (int r = 0; r < 4; ++r) {
            float x = acc[f][r] + bs;
            if (EPI == 1) x = gelu_f(x);
            if (OUTBF) Cb[(long)(mr + r)*ldc + n] = f2bf(x);
            else       Cf[(long)(mr + r)*ldc + n] = x;
        }
    }
}

// ---------------- control: f = [sf(256), cf(128)] bf16 ----------------
__device__ void control_dev(char* smem, int b, const Ptrs& p)
{
    float* bc  = (float*)smem;        // 8
    float* cf1 = bc + 8;              // 64
    const int tid = threadIdx.x;
    if (tid < 6) bc[tid] = p.BC[b*6 + tid];
    __syncthreads();
    {
        int s = tid >> 6;
        p.fbuf_bf[(long)b*384 + tid] = f2bf(gelu_f(bc[s]*p.sb_w[tid] + p.sb_b[tid]));
    }
    if (tid < 64) {
        cf1[tid] = gelu_f(bc[4]*p.cm_w1[tid] + bc[5]*p.cm_w1[64+tid] + p.cm_b1[tid]);
    }
    __syncthreads();
    if (tid < 128) {
        float acc = p.cm_b2[tid];
        #pragma unroll 8
        for (int i = 0; i < 64; ++i) acc = fmaf(cf1[i], p.cm_w2[i*128 + tid], acc);
        p.fbuf_bf[(long)b*384 + 256 + tid] = f2bf(gelu_f(acc));
    }
}

// ---------------- a_map = LN(relu(a_n @ a0_w + a0_b)) bf16 ----------------
__device__ void a_map_dev(char* smem, int bx, int v, const Ptrs& p)
{
    float* arow = (float*)smem;       // [4][64]
    const int w = threadIdx.x >> 6, lane = threadIdx.x & 63;
    const int b = bx*4 + w;
    arow[w*64 + lane] = p.a_n[((long)b*2 + v)*64 + lane];
    __syncthreads();
    float acc = p.a0_b[v*64 + lane];
    #pragma unroll 8
    for (int rp = 0; rp < 64; ++rp)
        acc = fmaf(arow[w*64 + rp], p.a0_w[((long)v*64 + rp)*64 + lane], acc);
    float x = fmaxf(acc, 0.0f);
    float mu = wave_sum(x) * (1.0f/64.0f);
    float d = x - mu;
    float var = wave_sum(d*d) * (1.0f/64.0f);
    float y = d * rsqrtf(var + 1e-5f) * p.a0_ln_g[v*64 + lane] + p.a0_ln_b[v*64 + lane];
    p.amap_bf[((long)v*512 + b)*64 + lane] = f2bf(y);
}

// ---------------- opj[v,d] = sum_e attn_ow[v,d,e]*proj_w[v,e] ----------------
__device__ void opj_dev(int oi, const Ptrs& p)
{
    const int tid = threadIdx.x;
    const int v = oi >> 3, dc = oi & 7;
    const int d = dc*64 + (tid >> 2);
    const int e0 = (tid & 3)*128;
    const float* row = p.attn_ow + ((long)v*512 + d)*512 + e0;
    const float* pj  = p.proj_w + v*512 + e0;
    float s = 0.f;
    #pragma unroll 8
    for (int j = 0; j < 128; ++j) s = fmaf(row[j], pj[j], s);
    s += __shfl_xor(s, 1, 64);
    s += __shfl_xor(s, 2, 64);
    if ((tid & 3) == 0) p.opj[v*512 + d] = s;
}

// ---------------- u0/u1: per-head matvecs of Wk against Wq_w / Wq_b ----------------
__device__ void u01_dev(int i, const Ptrs& p)
{
    const int tid = threadIdx.x;
    const int w = tid >> 6, lane = tid & 63;
    const int v = i >> 4, c = i & 15;            // 64-row chunk
    const float* wq = p.Wq_w + v*512;
    const float* wb = p.Wq_b + v*512;
    for (int pass = 0; pass < 16; ++pass) {
        const int n = c*64 + pass*4 + w;
        const float* row = p.Wk_w + ((long)v*1024 + n)*512 + lane*8;
        float4 a = *(const float4*)row, b = *(const float4*)(row + 4);
        float s0 = 0.f, s1 = 0.f;
        #pragma unroll
        for (int j = 0; j < 8; ++j) {
            float x = (j < 4) ? ((const float*)&a)[j] : ((const float*)&b)[j-4];
            s0 = fmaf(x, wq[lane*8 + j], s0);
            s1 = fmaf(x, wb[lane*8 + j], s1);
        }
        s0 += __shfl_xor(s0,1,64); s0 += __shfl_xor(s0,2,64); s0 += __shfl_xor(s0,4,64);
        s1 += __shfl_xor(s1,1,64); s1 += __shfl_xor(s1,2,64); s1 += __shfl_xor(s1,4,64);
        if ((lane & 7) == 0) {
            const int h = lane >> 3;
            p.u0[((long)v*1024 + n)*8 + h] = s0;
            p.u1[((long)v*1024 + n)*8 + h] = s1;
        }
    }
}

// ---------------- u2: per-head matvec of Wv against opj ----------------
__device__ void u2_dev(int i, const Ptrs& p)
{
    const int tid = threadIdx.x;
    const int w = tid >> 6, lane = tid & 63;
    const int v = i >> 4, c = i & 15;
    const float* oj = p.opj + v*512;
    for (int pass = 0; pass < 16; ++pass) {
        const int n = c*64 + pass*4 + w;
        const float* row = p.Wv_w + ((long)v*1024 + n)*512 + lane*8;
        float4 a = *(const float4*)row, b = *(const float4*)(row + 4);
        float s0 = 0.f;
        #pragma unroll
        for (int j = 0; j < 8; ++j) {
            float x = (j < 4) ? ((const float*)&a)[j] : ((const float*)&b)[j-4];
            s0 = fmaf(x, oj[lane*8 + j], s0);
        }
        s0 += __shfl_xor(s0,1,64); s0 += __shfl_xor(s0,2,64); s0 += __shfl_xor(s0,4,64);
        if ((lane & 7) == 0) p.u2[((long)v*1024 + n)*8 + (lane >> 3)] = s0;
    }
}

// ---------------- kq/qq partials: Phi^T @ u0/u1 over an n-chunk of 128 ----------------
__device__ void kqqq_dev(int i, const Ptrs& p)
{
    const int tid = threadIdx.x;
    const int v = i >> 3, c = i & 7;
    const int r = tid & 63, hp = tid >> 6;
    const int h0 = hp*2, h1 = h0 + 1;
    float k0=0.f,k1=0.f,q0=0.f,q1=0.f;
    const float* Pb = p.Phi + ((long)v*1024 + c*128)*64 + r;
    const float* U0 = p.u0 + ((long)v*1024 + c*128)*8;
    const float* U1 = p.u1 + ((long)v*1024 + c*128)*8;
    #pragma unroll 4
    for (int n = 0; n < 128; ++n) {
        float phi = Pb[(long)n*64];
        k0 = fmaf(phi, U0[n*8+h0], k0); k1 = fmaf(phi, U0[n*8+h1], k1);
        q0 = fmaf(phi, U1[n*8+h0], q0); q1 = fmaf(phi, U1[n*8+h1], q1);
    }
    const long o = (((long)v*8 + c)*64 + r)*8;
    p.pkq[o+h0] = k0; p.pkq[o+h1] = k1;
    p.pqq[o+h0] = q0; p.pqq[o+h1] = q1;
}

// ---------------- vo partials: Phi^T @ u2 over an n-chunk of 128 ----------------
__device__ void pvo_dev(int i, const Ptrs& p)
{
    const int tid = threadIdx.x;
    const int v = i >> 3, c = i & 7;
    const int r = tid & 63, hp = tid >> 6;
    const int h0 = hp*2, h1 = h0 + 1;
    float a0 = 0.f, a1 = 0.f;
    const float* Pb = p.Phi + ((long)v*1024 + c*128)*64 + r;
    const float* U2 = p.u2 + ((long)v*1024 + c*128)*8;
    #pragma unroll 4
    for (int n = 0; n < 128; ++n) {
        float phi = Pb[(long)n*64];
        a0 = fmaf(phi, U2[n*8+h0], a0);
        a1 = fmaf(phi, U2[n*8+h1], a1);
    }
    const long o = (((long)v*8 + c)*64 + r)*8;
    p.pvo[o+h0] = a0; p.pvo[o+h1] = a1;
}

// ---------------- consts final (run in consumer blocks) ----------------
__device__ float2 consts_final_dev(char* smem, int v, const Ptrs& p)
{
    const int tid = threadIdx.x;
    const int r = tid & 63, hp = tid >> 6;
    const int h0 = hp*2, h1 = h0 + 1;
    float k0=0.f,k1=0.f,q0=0.f,q1=0.f,w0=0.f,w1=0.f;
    #pragma unroll
    for (int c = 0; c < 8; ++c) {
        const long o = (((long)v*8 + c)*64 + r)*8;
        k0 += p.pkq[o+h0]; k1 += p.pkq[o+h1];
        q0 += p.pqq[o+h0]; q1 += p.pqq[o+h1];
        w0 += p.pvo[o+h0]; w1 += p.pvo[o+h1];
    }
    float bk0=0.f,bk1=0.f,bq0=0.f,bq1=0.f,bv0=0.f,bv1=0.f;
    #pragma unroll 8
    for (int j = 0; j < 64; ++j) {
        float b0 = p.Wk_b[v*512 + h0*64 + j], b1 = p.Wk_b[v*512 + h1*64 + j];
        bk0 = fmaf(b0, p.Wq_w[v*512 + h0*64 + j], bk0);
        bk1 = fmaf(b1, p.Wq_w[v*512 + h1*64 + j], bk1);
        bq0 = fmaf(b0, p.Wq_b[v*512 + h0*64 + j], bq0);
        bq1 = fmaf(b1, p.Wq_b[v*512 + h1*64 + j], bq1);
        float c0v = p.Wv_b[v*512 + h0*64 + j], c1v = p.Wv_b[v*512 + h1*64 + j];
        bv0 = fmaf(c0v, p.opj[v*512 + h0*64 + j], bv0);
        bv1 = fmaf(c1v, p.opj[v*512 + h1*64 + j], bv1);
    }
    w0 += bv0; w1 += bv1;
    k0 += bk0; k1 += bk1; q0 += bq0; q1 += bq1;
    float s1 = k0*w0 + k1*w1;
    float s0 = q0*w0 + q1*w1;
    float sA = p.attn_ob[v*512 + tid]*p.proj_w[v*512 + tid]
             + p.attn_ob[v*512 + 256 + tid]*p.proj_w[v*512 + 256 + tid];
    s1 = wave_sum(s1); s0 = wave_sum(s0); sA = wave_sum(sA);
    float* red = (float*)smem;
    const int w = tid >> 6, l = tid & 63;
    __syncthreads();
    if (l == 0) { red[w] = s1; red[4+w] = s0; red[8+w] = sA; }
    __syncthreads();
    float S1 = red[0]+red[1]+red[2]+red[3];
    float S0 = red[4]+red[5]+red[6]+red[7];
    float SA = red[8]+red[9]+red[10]+red[11];
    __syncthreads();
    const float inv = 0.044194173824159216f;   // 1/sqrt(512)
    float2 res;
    res.x = S1*inv;
    res.y = (S0 + SA)*inv + p.proj_b[v];
    return res;
}

// ---------------- bias2 + parts: once, 1 block ----------------
__device__ void bias2_dev(char* smem, const Ptrs& p)
{
    const float2 cv0 = consts_final_dev(smem, 0, p);
    const float2 cv1 = consts_final_dev(smem, 1, p);
    if (threadIdx.x == 0) {
        p.parts[0] = cv0.x; p.parts[1] = cv1.x;
        p.parts[2] = cv0.y; p.parts[3] = cv1.y;
    }
    #pragma unroll
    for (int k = 0; k < 8; ++k) {
        const int n2 = k*256 + threadIdx.x;
        const float c0 = (n2 >> 10) ? cv1.y : cv0.y;
        p.bias2[n2] = p.fu_b4[n2] + c0*p.phirs[n2];
    }
}

// ================= stage kernels =================
// stage0: cvt tiles [0, 72) + control + a_map + opj + u01
__global__ __launch_bounds__(256) void stage0_k(Ptrs p, CvtArgs ca, int ncvt)
{
    extern __shared__ char smem[];
    const int bx = blockIdx.x;
    if (bx < ncvt) {
        cvt_tile(smem, bx, ca, p);
    } else if (bx < ncvt + 512) {
        control_dev(smem, bx - ncvt, p);
    } else if (bx < ncvt + 768) {
        int i = bx - ncvt - 512;
        a_map_dev(smem, i & 127, i >> 7, p);
    } else if (bx < ncvt + 784) {
        opj_dev(bx - ncvt - 768, p);
    } else {
        u01_dev(bx - ncvt - 784, p);            // 32 blocks
    }
}

// stage1: fu1(32) | ffn1(128) | u2(32) | kqqq(16) | cvt tiles [72, 360)
__global__ __launch_bounds__(256) void stage1_k(Ptrs p, CvtArgs ca)
{
    extern __shared__ char smem[];
    const int bx = blockIdx.x;
    if (bx < 32) {                              // fu1: M=512,N=256,K=384
        bgemm_dev(smem, p.fbuf_bf, p.w_fu1t, p.fu_b1, p.hA_bf,
                  (bx>>2)*64, (bx&3)*64, 384, 256, 1, true);
    } else if (bx < 160) {                      // ffn1: per-v M=512,N=512,K=64
        int i = bx - 32; int v = i >> 6; i &= 63;
        bgemm_dev(smem, p.amap_bf + (long)v*32768, p.w_ffn1t + (long)v*32768,
                  p.ffn_b1 + v*512, (void*)(p.h1_bf + (long)v*262144),
                  (i>>3)*64, (i&7)*64, 64, 512, 1, true);
    } else if (bx < 192) {
        u2_dev(bx - 160, p);                    // 32 blocks
    } else if (bx < 208) {
        kqqq_dev(bx - 192, p);                  // 16 blocks
    } else {
        cvt_tile(smem, 72 + (bx - 208), ca, p); // 288 blocks
    }
}

// stage2: fu2(64) | ffn2(128) | pvo(16) | cvt tiles [360, 408)
__global__ __launch_bounds__(256) void stage2_k(Ptrs p, CvtArgs ca)
{
    extern __shared__ char smem[];
    const int bx = blockIdx.x;
    if (bx < 64) {                              // fu2: M=512,N=512,K=256
        bgemm_dev(smem, p.hA_bf, p.w_fu2t, p.fu_b2, p.hB_bf,
                  (bx>>3)*64, (bx&7)*64, 256, 512, 1, true);
    } else if (bx < 192) {                      // ffn2: per-v M=512,N=512,K=512
        int i = bx - 64; int v = i >> 6; i &= 63;
        bgemm_dev(smem, p.h1_bf + (long)v*262144, p.w_ffn2t + (long)v*262144,
                  p.ffn_b2 + v*512, (void*)(p.h2_bf + (long)v*262144),
                  (i>>3)*64, (i&7)*64, 512, 512, 1, true);
    } else if (bx < 208) {
        pvo_dev(bx - 192, p);                   // 16 blocks
    } else {
        cvt_tile(smem, 360 + (bx - 208), ca, p); // 48 blocks
    }
}

__global__ __launch_bounds__(256) void stage3_k(Ptrs p)
{
    extern __shared__ char smem[];
    const int bx = blockIdx.x;
    if (bx < 32) {                              // fu3 -> Abig cols [128:384)
        bgemm_dev(smem, p.hB_bf, p.w_fu3t, p.fu_b3, (void*)(p.Abig + 128),
                  (bx>>2)*64, (bx&3)*64, 512, 384, 1, true);
    } else if (bx < 48) {                       // o-GEMM: per-v M=512,N=64,K=512
        int i = bx - 32; int v = i >> 3; int m = i & 7;
        bgemm_dev(smem, p.h2_bf + (long)v*262144, p.w_ffn3t + (long)v*32768,
                  p.ffn_b3 + v*64, (void*)(p.obuf + (long)v*32768),
                  m*64, 0, 512, 64, 0, false);
    } else {
        bias2_dev(smem, p);                     // 1 block (also writes parts)
    }
}

// ofuse finish: u = LN(o+amap); Abig[:,v*64+j] = am*(1+c1) + alpha*u
__global__ __launch_bounds__(256) void stage3b_k(Ptrs p)
{
    const int g = blockIdx.x*4 + (threadIdx.x >> 6);   // 1024 wave-rows
    const int lane = threadIdx.x & 63;
    const int v = g >> 9, b = g & 511;
    const float o  = p.obuf[((long)v*512 + b)*64 + lane];
    const float am = bf2f(p.amap_bf[((long)v*512 + b)*64 + lane]);
    float t = o + am;
    float mu = wave_sum(t) * (1.0f/64.0f);
    float dd = t - mu;
    float var = wave_sum(dd*dd) * (1.0f/64.0f);
    float u = dd * rsqrtf(var + 1e-5f) * p.ffn_ln_g[v*64+lane] + p.ffn_ln_b[v*64+lane];
    const float c1 = p.parts[v];
    p.Abig[(long)b*384 + v*64 + lane] = f2bf(am*(1.0f + c1) + p.alpha[v]*u);
}

__global__ __launch_bounds__(256) void stage4_k(Ptrs p)
{
    extern __shared__ char smem[];              // big GEMM M=512,N=2048,K=384
    const int bx = blockIdx.x;
    bgemm_dev(smem, p.Abig, p.Bbig, p.bias2, (void*)p.out,
              (bx>>5)*64, (bx&31)*64, 384, 2048, 0, false);
}

extern "C" void kernel_launch(void* const* d_in, const int* in_sizes, int n_in,
                              void* d_out, int out_size, void* d_ws, size_t ws_size,
                              hipStream_t stream)
{
    const float* a_n      = (const float*)d_in[0];
    const float* BC       = (const float*)d_in[1];
    const float* Phi      = (const float*)d_in[2];
    const float* Wq_w     = (const float*)d_in[3];
    const float* Wq_b     = (const float*)d_in[4];
    const float* Wk_w     = (const float*)d_in[5];
    const float* Wk_b     = (const float*)d_in[6];
    const float* Wv_w     = (const float*)d_in[7];
    const float* Wv_b     = (const float*)d_in[8];
    const float* attn_ow  = (const float*)d_in[9];
    const float* attn_ob  = (const float*)d_in[10];
    const float* proj_w   = (const float*)d_in[11];
    const float* proj_b   = (const float*)d_in[12];
    const float* ffn_w1   = (const float*)d_in[13];
    const float* ffn_b1   = (const float*)d_in[14];
    const float* ffn_w2   = (const float*)d_in[15];
    const float* ffn_b2   = (const float*)d_in[16];
    const float* ffn_w3   = (const float*)d_in[17];
    const float* ffn_b3   = (const float*)d_in[18];
    const float* ffn_ln_g = (const float*)d_in[19];
    const float* ffn_ln_b = (const float*)d_in[20];
    const float* a0_w     = (const float*)d_in[21];
    const float* a0_b     = (const float*)d_in[22];
    const float* a0_ln_g  = (const float*)d_in[23];
    const float* a0_ln_b  = (const float*)d_in[24];
    const float* alpha    = (const float*)d_in[25];
    const float* sb_w     = (const float*)d_in[26];
    const float* sb_b     = (const float*)d_in[27];
    const float* cm_w1    = (const float*)d_in[28];
    const float* cm_b1    = (const float*)d_in[29];
    const float* cm_w2    = (const float*)d_in[30];
    const float* cm_b2    = (const float*)d_in[31];
    const float* fu_w1    = (const float*)d_in[32];
    const float* fu_b1    = (const float*)d_in[33];
    const float* fu_w2    = (const float*)d_in[34];
    const float* fu_b2    = (const float*)d_in[35];
    const float* fu_w3    = (const float*)d_in[36];
    const float* fu_b3    = (const float*)d_in[37];
    const float* fu_w4    = (const float*)d_in[38];
    const float* fu_b4    = (const float*)d_in[39];

    float* ws = (float*)d_ws;
    Ptrs p;
    p.a_n = a_n; p.BC = BC; p.Phi = Phi; p.Wq_w = Wq_w; p.Wq_b = Wq_b;
    p.Wk_w = Wk_w; p.Wk_b = Wk_b; p.Wv_w = Wv_w; p.Wv_b = Wv_b;
    p.attn_ow = attn_ow; p.attn_ob = attn_ob; p.proj_w = proj_w; p.proj_b = proj_b;
    p.ffn_w3 = ffn_w3; p.ffn_b3 = ffn_b3; p.ffn_ln_g = ffn_ln_g; p.ffn_ln_b = ffn_ln_b;
    p.a0_w = a0_w; p.a0_b = a0_b; p.a0_ln_g = a0_ln_g; p.a0_ln_b = a0_ln_b;
    p.alpha = alpha; p.sb_w = sb_w; p.sb_b = sb_b;
    p.cm_w1 = cm_w1; p.cm_b1 = cm_b1; p.cm_w2 = cm_w2; p.cm_b2 = cm_b2;
    p.fu_b1 = fu_b1; p.fu_b2 = fu_b2; p.fu_b3 = fu_b3; p.fu_b4 = fu_b4;
    p.ffn_b1 = ffn_b1; p.ffn_b2 = ffn_b2;

    p.opj     = ws;                              // 1024
    p.u0      = ws + 1024;                       // 16384 [v][1024][8]
    p.u1      = ws + 17408;                      // 16384
    p.u2      = ws + 33792;                      // 16384
    p.pkq     = ws + 50176;                      // 8192 [v][8][64][8]
    p.pqq     = ws + 58368;                      // 8192
    p.pvo     = ws + 66560;                      // 8192
    p.phirs   = ws + 74752;                      // 2048
    p.bias2   = ws + 76800;                      // 2048
    p.parts   = ws + 78848;                      // 128 (4 used)
    p.amap_bf = (ushort_t*)(ws + 78976);         // 65536 ush
    p.h1_bf   = (ushort_t*)(ws + 111744);        // 524288 ush
    p.h2_bf   = (ushort_t*)(ws + 373888);        // 524288 ush
    p.fbuf_bf = (ushort_t*)(ws + 636032);        // 196608 ush
    p.hA_bf   = (ushort_t*)(ws + 734336);        // 131072 ush
    p.hB_bf   = (ushort_t*)(ws + 799872);        // 262144 ush
    p.w_fu1t  = (ushort_t*)(ws + 930944);        // 98304  [256][384]
    p.w_fu2t  = (ushort_t*)(ws + 980096);        // 131072 [512][256]
    p.w_fu3t  = (ushort_t*)(ws + 1045632);       // 131072 [256][512]
    p.w_ffn1t = (ushort_t*)(ws + 1111168);       // 65536  [v][512][64]
    p.w_ffn2t = (ushort_t*)(ws + 1143936);       // 524288 [v][512][512]
    p.w_ffn3t = (ushort_t*)(ws + 1406080);       // 65536  [v][64][512]
    p.Abig    = (ushort_t*)(ws + 1438848);       // 196608 [512][384]
    p.Bbig    = (ushort_t*)(ws + 1537152);       // 786432 [2048][384]
    p.obuf    = ws + 1930368;                    // 65536 fp32 [v][512][64]
    p.out     = (float*)d_out;

    CvtArgs ca;
    auto set = [&](int i, const float* s, ushort_t* dst, int K, int N,
                   int mode, int ldd, int coff) {
        ca.d[i].src = s; ca.d[i].dst = dst; ca.d[i].K = K; ca.d[i].N = N;
        ca.d[i].mode = mode; ca.d[i].ldd = ldd; ca.d[i].coff = coff;
    };
    // ---- stage0 tiles [0, 72): weights consumed in stage1/stage2-start ----
    set(0,  fu_w1,           p.w_fu1t,           384, 256,  0, 384, 0);   // 24
    set(1,  fu_w2,           p.w_fu2t,           256, 512,  0, 256, 0);   // 32
    set(2,  ffn_w1,          p.w_ffn1t,          64,  512,  0, 64,  0);   // 8
    set(3,  ffn_w1 + 32768,  p.w_ffn1t + 32768,  64,  512,  0, 64,  0);   // 8
    // ---- stage1 tiles [72, 360): consumed in stage2/3/4 ----
    set(4,  fu_w4,           p.Bbig,             256, 2048, 0, 384, 128); // 128
    set(5,  Phi,             p.Bbig,             0,    0,   2, 384, 0);   // 16 (v=0)
    set(6,  Phi + 65536,     p.Bbig + (long)1024*384, 1024, 0, 2, 384, 64); // 16 (v=1)
    set(7,  ffn_w2,          p.w_ffn2t,          512, 512,  0, 512, 0);   // 64
    set(8,  ffn_w2 + 262144, p.w_ffn2t + 262144, 512, 512,  0, 512, 0);   // 64
    // ---- stage2 tiles [360, 408): consumed in stage3 ----
    set(9,  fu_w3,           p.w_fu3t,           512, 256,  0, 512, 0);   // 32
    set(10, ffn_w3,          p.w_ffn3t,          512, 64,   0, 512, 0);   // 8
    set(11, ffn_w3 + 32768,  p.w_ffn3t + 32768,  512, 64,   0, 512, 0);   // 8
    const int tl[12] = {24,32,8,8, 128,16,16,64,64, 32,8,8};
    ca.cum[0] = 0;
    for (int i = 0; i < 12; ++i) ca.cum[i+1] = ca.cum[i] + tl[i];
    const int ncvt0 = 72;                        // stage0 share

    stage0_k <<<ncvt0 + 816, 256, 16896, stream>>>(p, ca, ncvt0);
    stage1_k <<<496,         256, 20480, stream>>>(p, ca);
    stage2_k <<<256,         256, 20480, stream>>>(p, ca);
    stage3_k <<<49,          256, 20480, stream>>>(p);
    stage3b_k<<<256,         256, 0,     stream>>>(p);
    stage4_k <<<256,         256, 20480, stream>>>(p);
}

// Round 14
// 67.600 us; speedup vs baseline: 1.1886x; 1.0055x over previous
//
#include <hip/hip_runtime.h>
#include <hip/hip_bf16.h>
#include <math.h>

// Shapes (fixed): B=512, V=2, NX=1024, R=64, D=512, H=8, S=4, NC=2, HS=64, FIN=384

typedef unsigned short ushort_t;
using short8 = __attribute__((ext_vector_type(8))) short;
using f32x4  = __attribute__((ext_vector_type(4))) float;

__device__ __forceinline__ float gelu_f(float x) {
    float x3 = x*x*x;
    return 0.5f*x*(1.0f + tanhf(0.7978845608028654f*(x + 0.044715f*x3)));
}

__device__ __forceinline__ float wave_sum(float x) {
    #pragma unroll
    for (int m = 32; m >= 1; m >>= 1) x += __shfl_xor(x, m, 64);
    return x;
}

__device__ __forceinline__ ushort_t f2bf(float x) {
    unsigned u = __float_as_uint(x);
    unsigned r = (u + 0x7FFFu + ((u >> 16) & 1u)) >> 16;   // RNE
    return (ushort_t)r;
}
__device__ __forceinline__ float bf2f(ushort_t h) {
    return __uint_as_float(((unsigned)h) << 16);
}

// ---------------- pointer bundle ----------------
struct Ptrs {
    const float *a_n, *BC, *Phi, *Wq_w, *Wq_b, *Wk_w, *Wk_b, *Wv_w, *Wv_b,
                *attn_ow, *attn_ob, *proj_w, *proj_b,
                *ffn_w3, *ffn_b3, *ffn_ln_g, *ffn_ln_b,
                *a0_w, *a0_b, *a0_ln_g, *a0_ln_b, *alpha,
                *sb_w, *sb_b, *cm_w1, *cm_b1, *cm_w2, *cm_b2,
                *fu_b1, *fu_b2, *fu_b3, *fu_b4, *ffn_b1, *ffn_b2;
    float *opj, *u0, *u1, *u2, *pkq, *pqq, *pvo, *phirs, *bias2, *parts,
          *obuf, *out;
    ushort_t *amap_bf, *h1_bf, *h2_bf, *fbuf_bf, *hA_bf, *hB_bf;
    ushort_t *w_fu1t, *w_fu2t, *w_fu3t, *w_ffn1t, *w_ffn2t, *w_ffn3t,
             *Abig, *Bbig;
};

// ---------------- cvt descriptors ----------------
// mode 0: transpose fp32 [K][N] 64x64 tiles -> bf16 [N][ldd] at col offset coff
// mode 2: Phi rows -> Bbig slab (+zero other slab) + phirs rowsums; K = phirs base
struct CvtDesc { const float* src; ushort_t* dst; int K, N, mode, ldd, coff; };
struct CvtArgs { CvtDesc d[12]; int cum[13]; };

__device__ void cvt_tile(char* smem, int gtile, const CvtArgs& ca, const Ptrs& p)
{
    int e = 0;
    while (gtile >= ca.cum[e+1]) ++e;
    const CvtDesc d = ca.d[e];
    const int tile = gtile - ca.cum[e];
    const int t = threadIdx.x;
    if (d.mode == 2) {
        const int row = t >> 2, q = t & 3;          // 64 rows/block, 4 thr/row
        const float* s = d.src + (long)(tile*64 + row)*64 + q*16;
        ushort_t* dst  = d.dst + (long)(tile*64 + row)*384 + d.coff + q*16;
        ushort_t* dz   = d.dst + (long)(tile*64 + row)*384 + (64 - d.coff) + q*16;
        float sum = 0.f;
        #pragma unroll
        for (int i = 0; i < 4; ++i) {
            float4 x = *(const float4*)(s + i*4);
            ushort4 w; w.x=f2bf(x.x); w.y=f2bf(x.y); w.z=f2bf(x.z); w.w=f2bf(x.w);
            *(ushort4*)(dst + i*4) = w;
            ushort4 z; z.x=0; z.y=0; z.z=0; z.w=0;
            *(ushort4*)(dz + i*4) = z;
            sum += x.x + x.y + x.z + x.w;
        }
        sum += __shfl_xor(sum, 1, 64);
        sum += __shfl_xor(sum, 2, 64);
        if (q == 0) p.phirs[d.K + tile*64 + row] = sum;
    } else {
        // 64x64 fp32 transpose tile -> bf16 [N][ldd]
        float* tl = (float*)smem;                   // [64][65]
        const int ntn = d.N >> 6;
        const int kt = tile / ntn, nt = tile % ntn;
        const int r = t >> 2, c0 = (t & 3) * 16;
        #pragma unroll
        for (int i = 0; i < 4; ++i) {
            float4 v = *(const float4*)(d.src + (long)(kt*64 + r)*d.N + nt*64 + c0 + i*4);
            tl[r*65 + c0 + i*4 + 0] = v.x;
            tl[r*65 + c0 + i*4 + 1] = v.y;
            tl[r*65 + c0 + i*4 + 2] = v.z;
            tl[r*65 + c0 + i*4 + 3] = v.w;
        }
        __syncthreads();
        #pragma unroll
        for (int i = 0; i < 4; ++i) {
            ushort4 w;
            w.x = f2bf(tl[(c0 + i*4 + 0)*65 + r]);
            w.y = f2bf(tl[(c0 + i*4 + 1)*65 + r]);
            w.z = f2bf(tl[(c0 + i*4 + 2)*65 + r]);
            w.w = f2bf(tl[(c0 + i*4 + 3)*65 + r]);
            *(ushort4*)(d.dst + (long)(nt*64 + r)*d.ldd + d.coff + kt*64 + c0 + i*4) = w;
        }
    }
}

// ---------------- bf16 MFMA GEMM (device) ----------------
// EPI: 0 = +bias, 1 = gelu(+bias). OUTBF: bf16 out else fp32.
__device__ void bgemm_dev(char* smem_,
    const ushort_t* __restrict__ A, const ushort_t* __restrict__ B,
    const float* __restrict__ bias,
    void* __restrict__ Cv, int m0, int n0, int K, int ldc,
    int EPI, bool OUTBF)
{
    ushort_t* lds = (ushort_t*)smem_;   // [2][2][64][40]
    const int tid = threadIdx.x;
    const int w = tid >> 6, l = tid & 63;
    const int ml = l & 15, kg = l >> 4;
    const int srow = tid >> 2, sslot = tid & 3;
    const ushort_t* Ag = A + (long)(m0 + srow)*K + sslot*8;
    const ushort_t* Bg = B + (long)(n0 + srow)*K + sslot*8;
    auto L = [&](int buf, int ab, int row, int col) {
        return lds + (((buf*2 + ab)*64 + row)*40 + col);
    };
    f32x4 acc[4] = {};
    const int nt = K >> 5;
    int4 ra = *(const int4*)Ag;
    int4 rb = *(const int4*)Bg;
    *(int4*)L(0,0,srow,sslot*8) = ra;
    *(int4*)L(0,1,srow,sslot*8) = rb;
    __syncthreads();
    for (int t = 0; t < nt; ++t) {
        const int cur = t & 1;
        if (t + 1 < nt) {
            ra = *(const int4*)(Ag + (t+1)*32);
            rb = *(const int4*)(Bg + (t+1)*32);
        }
        short8 af = *(const short8*)L(cur,0,w*16 + ml,kg*8);
        #pragma unroll
        for (int f = 0; f < 4; ++f) {
            short8 bfr = *(const short8*)L(cur,1,f*16 + ml,kg*8);
            acc[f] = __builtin_amdgcn_mfma_f32_16x16x32_bf16(af, bfr, acc[f], 0, 0, 0);
        }
        if (t + 1 < nt) {
            *(int4*)L(cur^1,0,srow,sslot*8) = ra;
            *(int4*)L(cur^1,1,srow,sslot*8) = rb;
            __syncthreads();
        }
    }
    float* Cf = (float*)Cv; ushort_t* Cb = (ushort_t*)Cv;
    const int mr = m0 + w*16 + kg*4;
    const int nc = n0 + ml;
    #pragma unroll
    for (int f = 0; f < 4; ++f) {
        const int n = nc + f*16;
        const float bs = bias[n];
        #pragma unroll
        for (int r = 0; r < 4; ++r) {
            float x = acc[f][r] + bs;
            if (EPI == 1) x = gelu_f(x);
            if (OUTBF) Cb[(long)(mr + r)*ldc + n] = f2bf(x);
            else       Cf[(long)(mr + r)*ldc + n] = x;
        }
    }
}

// ---------------- control: f = [sf(256), cf(128)] bf16 ----------------
__device__ void control_dev(char* smem, int b, const Ptrs& p)
{
    float* bc  = (float*)smem;        // 8
    float* cf1 = bc + 8;              // 64
    const int tid = threadIdx.x;
    if (tid < 6) bc[tid] = p.BC[b*6 + tid];
    __syncthreads();
    {
        int s = tid >> 6;
        p.fbuf_bf[(long)b*384 + tid] = f2bf(gelu_f(bc[s]*p.sb_w[tid] + p.sb_b[tid]));
    }
    if (tid < 64) {
        cf1[tid] = gelu_f(bc[4]*p.cm_w1[tid] + bc[5]*p.cm_w1[64+tid] + p.cm_b1[tid]);
    }
    __syncthreads();
    if (tid < 128) {
        float acc = p.cm_b2[tid];
        #pragma unroll 8
        for (int i = 0; i < 64; ++i) acc = fmaf(cf1[i], p.cm_w2[i*128 + tid], acc);
        p.fbuf_bf[(long)b*384 + 256 + tid] = f2bf(gelu_f(acc));
    }
}

// ---------------- a_map = LN(relu(a_n @ a0_w + a0_b)) bf16 ----------------
__device__ void a_map_dev(char* smem, int bx, int v, const Ptrs& p)
{
    float* arow = (float*)smem;       // [4][64]
    const int w = threadIdx.x >> 6, lane = threadIdx.x & 63;
    const int b = bx*4 + w;
    arow[w*64 + lane] = p.a_n[((long)b*2 + v)*64 + lane];
    __syncthreads();
    float acc = p.a0_b[v*64 + lane];
    #pragma unroll 8
    for (int rp = 0; rp < 64; ++rp)
        acc = fmaf(arow[w*64 + rp], p.a0_w[((long)v*64 + rp)*64 + lane], acc);
    float x = fmaxf(acc, 0.0f);
    float mu = wave_sum(x) * (1.0f/64.0f);
    float d = x - mu;
    float var = wave_sum(d*d) * (1.0f/64.0f);
    float y = d * rsqrtf(var + 1e-5f) * p.a0_ln_g[v*64 + lane] + p.a0_ln_b[v*64 + lane];
    p.amap_bf[((long)v*512 + b)*64 + lane] = f2bf(y);
}

// ---------------- opj[v,d] = sum_e attn_ow[v,d,e]*proj_w[v,e] ----------------
__device__ void opj_dev(int oi, const Ptrs& p)
{
    const int tid = threadIdx.x;
    const int v = oi >> 3, dc = oi & 7;
    const int d = dc*64 + (tid >> 2);
    const int e0 = (tid & 3)*128;
    const float* row = p.attn_ow + ((long)v*512 + d)*512 + e0;
    const float* pj  = p.proj_w + v*512 + e0;
    float s = 0.f;
    #pragma unroll 8
    for (int j = 0; j < 128; ++j) s = fmaf(row[j], pj[j], s);
    s += __shfl_xor(s, 1, 64);
    s += __shfl_xor(s, 2, 64);
    if ((tid & 3) == 0) p.opj[v*512 + d] = s;
}

// ---------------- u0/u1: per-head matvecs of Wk against Wq_w / Wq_b ----------------
__device__ void u01_dev(int i, const Ptrs& p)
{
    const int tid = threadIdx.x;
    const int w = tid >> 6, lane = tid & 63;
    const int v = i >> 4, c = i & 15;            // 64-row chunk
    const float* wq = p.Wq_w + v*512;
    const float* wb = p.Wq_b + v*512;
    for (int pass = 0; pass < 16; ++pass) {
        const int n = c*64 + pass*4 + w;
        const float* row = p.Wk_w + ((long)v*1024 + n)*512 + lane*8;
        float4 a = *(const float4*)row, b = *(const float4*)(row + 4);
        float s0 = 0.f, s1 = 0.f;
        #pragma unroll
        for (int j = 0; j < 8; ++j) {
            float x = (j < 4) ? ((const float*)&a)[j] : ((const float*)&b)[j-4];
            s0 = fmaf(x, wq[lane*8 + j], s0);
            s1 = fmaf(x, wb[lane*8 + j], s1);
        }
        s0 += __shfl_xor(s0,1,64); s0 += __shfl_xor(s0,2,64); s0 += __shfl_xor(s0,4,64);
        s1 += __shfl_xor(s1,1,64); s1 += __shfl_xor(s1,2,64); s1 += __shfl_xor(s1,4,64);
        if ((lane & 7) == 0) {
            const int h = lane >> 3;
            p.u0[((long)v*1024 + n)*8 + h] = s0;
            p.u1[((long)v*1024 + n)*8 + h] = s1;
        }
    }
}

// ---------------- u2: per-head matvec of Wv against opj ----------------
__device__ void u2_dev(int i, const Ptrs& p)
{
    const int tid = threadIdx.x;
    const int w = tid >> 6, lane = tid & 63;
    const int v = i >> 4, c = i & 15;
    const float* oj = p.opj + v*512;
    for (int pass = 0; pass < 16; ++pass) {
        const int n = c*64 + pass*4 + w;
        const float* row = p.Wv_w + ((long)v*1024 + n)*512 + lane*8;
        float4 a = *(const float4*)row, b = *(const float4*)(row + 4);
        float s0 = 0.f;
        #pragma unroll
        for (int j = 0; j < 8; ++j) {
            float x = (j < 4) ? ((const float*)&a)[j] : ((const float*)&b)[j-4];
            s0 = fmaf(x, oj[lane*8 + j], s0);
        }
        s0 += __shfl_xor(s0,1,64); s0 += __shfl_xor(s0,2,64); s0 += __shfl_xor(s0,4,64);
        if ((lane & 7) == 0) p.u2[((long)v*1024 + n)*8 + (lane >> 3)] = s0;
    }
}

// ---------------- kq/qq partials: Phi^T @ u0/u1 over an n-chunk of 128 ----------------
__device__ void kqqq_dev(int i, const Ptrs& p)
{
    const int tid = threadIdx.x;
    const int v = i >> 3, c = i & 7;
    const int r = tid & 63, hp = tid >> 6;
    const int h0 = hp*2, h1 = h0 + 1;
    float k0=0.f,k1=0.f,q0=0.f,q1=0.f;
    const float* Pb = p.Phi + ((long)v*1024 + c*128)*64 + r;
    const float* U0 = p.u0 + ((long)v*1024 + c*128)*8;
    const float* U1 = p.u1 + ((long)v*1024 + c*128)*8;
    #pragma unroll 4
    for (int n = 0; n < 128; ++n) {
        float phi = Pb[(long)n*64];
        k0 = fmaf(phi, U0[n*8+h0], k0); k1 = fmaf(phi, U0[n*8+h1], k1);
        q0 = fmaf(phi, U1[n*8+h0], q0); q1 = fmaf(phi, U1[n*8+h1], q1);
    }
    const long o = (((long)v*8 + c)*64 + r)*8;
    p.pkq[o+h0] = k0; p.pkq[o+h1] = k1;
    p.pqq[o+h0] = q0; p.pqq[o+h1] = q1;
}

// ---------------- vo partials: Phi^T @ u2 over an n-chunk of 128 ----------------
__device__ void pvo_dev(int i, const Ptrs& p)
{
    const int tid = threadIdx.x;
    const int v = i >> 3, c = i & 7;
    const int r = tid & 63, hp = tid >> 6;
    const int h0 = hp*2, h1 = h0 + 1;
    float a0 = 0.f, a1 = 0.f;
    const float* Pb = p.Phi + ((long)v*1024 + c*128)*64 + r;
    const float* U2 = p.u2 + ((long)v*1024 + c*128)*8;
    #pragma unroll 4
    for (int n = 0; n < 128; ++n) {
        float phi = Pb[(long)n*64];
        a0 = fmaf(phi, U2[n*8+h0], a0);
        a1 = fmaf(phi, U2[n*8+h1], a1);
    }
    const long o = (((long)v*8 + c)*64 + r)*8;
    p.pvo[o+h0] = a0; p.pvo[o+h1] = a1;
}

// ---------------- consts final (run in consumer blocks) ----------------
__device__ float2 consts_final_dev(char* smem, int v, const Ptrs& p)
{
    const int tid = threadIdx.x;
    const int r = tid & 63, hp = tid >> 6;
    const int h0 = hp*2, h1 = h0 + 1;
    float k0=0.f,k1=0.f,q0=0.f,q1=0.f,w0=0.f,w1=0.f;
    #pragma unroll
    for (int c = 0; c < 8; ++c) {
        const long o = (((long)v*8 + c)*64 + r)*8;
        k0 += p.pkq[o+h0]; k1 += p.pkq[o+h1];
        q0 += p.pqq[o+h0]; q1 += p.pqq[o+h1];
        w0 += p.pvo[o+h0]; w1 += p.pvo[o+h1];
    }
    float bk0=0.f,bk1=0.f,bq0=0.f,bq1=0.f,bv0=0.f,bv1=0.f;
    #pragma unroll 8
    for (int j = 0; j < 64; ++j) {
        float b0 = p.Wk_b[v*512 + h0*64 + j], b1 = p.Wk_b[v*512 + h1*64 + j];
        bk0 = fmaf(b0, p.Wq_w[v*512 + h0*64 + j], bk0);
        bk1 = fmaf(b1, p.Wq_w[v*512 + h1*64 + j], bk1);
        bq0 = fmaf(b0, p.Wq_b[v*512 + h0*64 + j], bq0);
        bq1 = fmaf(b1, p.Wq_b[v*512 + h1*64 + j], bq1);
        float c0v = p.Wv_b[v*512 + h0*64 + j], c1v = p.Wv_b[v*512 + h1*64 + j];
        bv0 = fmaf(c0v, p.opj[v*512 + h0*64 + j], bv0);
        bv1 = fmaf(c1v, p.opj[v*512 + h1*64 + j], bv1);
    }
    w0 += bv0; w1 += bv1;
    k0 += bk0; k1 += bk1; q0 += bq0; q1 += bq1;
    float s1 = k0*w0 + k1*w1;
    float s0 = q0*w0 + q1*w1;
    float sA = p.attn_ob[v*512 + tid]*p.proj_w[v*512 + tid]
             + p.attn_ob[v*512 + 256 + tid]*p.proj_w[v*512 + 256 + tid];
    s1 = wave_sum(s1); s0 = wave_sum(s0); sA = wave_sum(sA);
    float* red = (float*)smem;
    const int w = tid >> 6, l = tid & 63;
    __syncthreads();
    if (l == 0) { red[w] = s1; red[4+w] = s0; red[8+w] = sA; }
    __syncthreads();
    float S1 = red[0]+red[1]+red[2]+red[3];
    float S0 = red[4]+red[5]+red[6]+red[7];
    float SA = red[8]+red[9]+red[10]+red[11];
    __syncthreads();
    const float inv = 0.044194173824159216f;   // 1/sqrt(512)
    float2 res;
    res.x = S1*inv;
    res.y = (S0 + SA)*inv + p.proj_b[v];
    return res;
}

// ---------------- bias2 + parts: once, 1 block ----------------
__device__ void bias2_dev(char* smem, const Ptrs& p)
{
    const float2 cv0 = consts_final_dev(smem, 0, p);
    const float2 cv1 = consts_final_dev(smem, 1, p);
    if (threadIdx.x == 0) {
        p.parts[0] = cv0.x; p.parts[1] = cv1.x;
        p.parts[2] = cv0.y; p.parts[3] = cv1.y;
    }
    #pragma unroll
    for (int k = 0; k < 8; ++k) {
        const int n2 = k*256 + threadIdx.x;
        const float c0 = (n2 >> 10) ? cv1.y : cv0.y;
        p.bias2[n2] = p.fu_b4[n2] + c0*p.phirs[n2];
    }
}

// ================= stage kernels =================
// stage0, longest-first order: u01(32) | opj(16) | a_map(256) | cvt(72) | control(512)
__global__ __launch_bounds__(256) void stage0_k(Ptrs p, CvtArgs ca)
{
    extern __shared__ char smem[];
    const int bx = blockIdx.x;
    if (bx < 32) {
        u01_dev(bx, p);
    } else if (bx < 48) {
        opj_dev(bx - 32, p);
    } else if (bx < 304) {
        int i = bx - 48;
        a_map_dev(smem, i & 127, i >> 7, p);
    } else if (bx < 376) {
        cvt_tile(smem, bx - 304, ca, p);        // tiles [0, 72)
    } else {
        control_dev(smem, bx - 376, p);         // 512 blocks (lightest -> tail)
    }
}

// stage1: fu1(32) | ffn1(128) | u2(32) | kqqq(16) | cvt tiles [72, 360)
__global__ __launch_bounds__(256) void stage1_k(Ptrs p, CvtArgs ca)
{
    extern __shared__ char smem[];
    const int bx = blockIdx.x;
    if (bx < 32) {                              // fu1: M=512,N=256,K=384
        bgemm_dev(smem, p.fbuf_bf, p.w_fu1t, p.fu_b1, p.hA_bf,
                  (bx>>2)*64, (bx&3)*64, 384, 256, 1, true);
    } else if (bx < 160) {                      // ffn1: per-v M=512,N=512,K=64
        int i = bx - 32; int v = i >> 6; i &= 63;
        bgemm_dev(smem, p.amap_bf + (long)v*32768, p.w_ffn1t + (long)v*32768,
                  p.ffn_b1 + v*512, (void*)(p.h1_bf + (long)v*262144),
                  (i>>3)*64, (i&7)*64, 64, 512, 1, true);
    } else if (bx < 192) {
        u2_dev(bx - 160, p);                    // 32 blocks
    } else if (bx < 208) {
        kqqq_dev(bx - 192, p);                  // 16 blocks
    } else {
        cvt_tile(smem, 72 + (bx - 208), ca, p); // 288 blocks
    }
}

// stage2: fu2(64) | ffn2(128) | pvo(16) | cvt tiles [360, 408)
__global__ __launch_bounds__(256) void stage2_k(Ptrs p, CvtArgs ca)
{
    extern __shared__ char smem[];
    const int bx = blockIdx.x;
    if (bx < 64) {                              // fu2: M=512,N=512,K=256
        bgemm_dev(smem, p.hA_bf, p.w_fu2t, p.fu_b2, p.hB_bf,
                  (bx>>3)*64, (bx&7)*64, 256, 512, 1, true);
    } else if (bx < 192) {                      // ffn2: per-v M=512,N=512,K=512
        int i = bx - 64; int v = i >> 6; i &= 63;
        bgemm_dev(smem, p.h1_bf + (long)v*262144, p.w_ffn2t + (long)v*262144,
                  p.ffn_b2 + v*512, (void*)(p.h2_bf + (long)v*262144),
                  (i>>3)*64, (i&7)*64, 512, 512, 1, true);
    } else if (bx < 208) {
        pvo_dev(bx - 192, p);                   // 16 blocks
    } else {
        cvt_tile(smem, 360 + (bx - 208), ca, p); // 48 blocks
    }
}

__global__ __launch_bounds__(256) void stage3_k(Ptrs p)
{
    extern __shared__ char smem[];
    const int bx = blockIdx.x;
    if (bx < 32) {                              // fu3 -> Abig cols [128:384)
        bgemm_dev(smem, p.hB_bf, p.w_fu3t, p.fu_b3, (void*)(p.Abig + 128),
                  (bx>>2)*64, (bx&3)*64, 512, 384, 1, true);
    } else if (bx < 48) {                       // o-GEMM: per-v M=512,N=64,K=512
        int i = bx - 32; int v = i >> 3; int m = i & 7;
        bgemm_dev(smem, p.h2_bf + (long)v*262144, p.w_ffn3t + (long)v*32768,
                  p.ffn_b3 + v*64, (void*)(p.obuf + (long)v*32768),
                  m*64, 0, 512, 64, 0, false);
    } else {
        bias2_dev(smem, p);                     // 1 block (also writes parts)
    }
}

// ofuse finish: u = LN(o+amap); Abig[:,v*64+j] = am*(1+c1) + alpha*u
__global__ __launch_bounds__(256) void stage3b_k(Ptrs p)
{
    const int g = blockIdx.x*4 + (threadIdx.x >> 6);   // 1024 wave-rows
    const int lane = threadIdx.x & 63;
    const int v = g >> 9, b = g & 511;
    const float o  = p.obuf[((long)v*512 + b)*64 + lane];
    const float am = bf2f(p.amap_bf[((long)v*512 + b)*64 + lane]);
    float t = o + am;
    float mu = wave_sum(t) * (1.0f/64.0f);
    float dd = t - mu;
    float var = wave_sum(dd*dd) * (1.0f/64.0f);
    float u = dd * rsqrtf(var + 1e-5f) * p.ffn_ln_g[v*64+lane] + p.ffn_ln_b[v*64+lane];
    const float c1 = p.parts[v];
    p.Abig[(long)b*384 + v*64 + lane] = f2bf(am*(1.0f + c1) + p.alpha[v]*u);
}

__global__ __launch_bounds__(256) void stage4_k(Ptrs p)
{
    extern __shared__ char smem[];              // big GEMM M=512,N=2048,K=384
    const int bx = blockIdx.x;
    bgemm_dev(smem, p.Abig, p.Bbig, p.bias2, (void*)p.out,
              (bx>>5)*64, (bx&31)*64, 384, 2048, 0, false);
}

extern "C" void kernel_launch(void* const* d_in, const int* in_sizes, int n_in,
                              void* d_out, int out_size, void* d_ws, size_t ws_size,
                              hipStream_t stream)
{
    const float* a_n      = (const float*)d_in[0];
    const float* BC       = (const float*)d_in[1];
    const float* Phi      = (const float*)d_in[2];
    const float* Wq_w     = (const float*)d_in[3];
    const float* Wq_b     = (const float*)d_in[4];
    const float* Wk_w     = (const float*)d_in[5];
    const float* Wk_b     = (const float*)d_in[6];
    const float* Wv_w     = (const float*)d_in[7];
    const float* Wv_b     = (const float*)d_in[8];
    const float* attn_ow  = (const float*)d_in[9];
    const float* attn_ob  = (const float*)d_in[10];
    const float* proj_w   = (const float*)d_in[11];
    const float* proj_b   = (const float*)d_in[12];
    const float* ffn_w1   = (const float*)d_in[13];
    const float* ffn_b1   = (const float*)d_in[14];
    const float* ffn_w2   = (const float*)d_in[15];
    const float* ffn_b2   = (const float*)d_in[16];
    const float* ffn_w3   = (const float*)d_in[17];
    const float* ffn_b3   = (const float*)d_in[18];
    const float* ffn_ln_g = (const float*)d_in[19];
    const float* ffn_ln_b = (const float*)d_in[20];
    const float* a0_w     = (const float*)d_in[21];
    const float* a0_b     = (const float*)d_in[22];
    const float* a0_ln_g  = (const float*)d_in[23];
    const float* a0_ln_b  = (const float*)d_in[24];
    const float* alpha    = (const float*)d_in[25];
    const float* sb_w     = (const float*)d_in[26];
    const float* sb_b     = (const float*)d_in[27];
    const float* cm_w1    = (const float*)d_in[28];
    const float* cm_b1    = (const float*)d_in[29];
    const float* cm_w2    = (const float*)d_in[30];
    const float* cm_b2    = (const float*)d_in[31];
    const float* fu_w1    = (const float*)d_in[32];
    const float* fu_b1    = (const float*)d_in[33];
    const float* fu_w2    = (const float*)d_in[34];
    const float* fu_b2    = (const float*)d_in[35];
    const float* fu_w3    = (const float*)d_in[36];
    const float* fu_b3    = (const float*)d_in[37];
    const float* fu_w4    = (const float*)d_in[38];
    const float* fu_b4    = (const float*)d_in[39];

    float* ws = (float*)d_ws;
    Ptrs p;
    p.a_n = a_n; p.BC = BC; p.Phi = Phi; p.Wq_w = Wq_w; p.Wq_b = Wq_b;
    p.Wk_w = Wk_w; p.Wk_b = Wk_b; p.Wv_w = Wv_w; p.Wv_b = Wv_b;
    p.attn_ow = attn_ow; p.attn_ob = attn_ob; p.proj_w = proj_w; p.proj_b = proj_b;
    p.ffn_w3 = ffn_w3; p.ffn_b3 = ffn_b3; p.ffn_ln_g = ffn_ln_g; p.ffn_ln_b = ffn_ln_b;
    p.a0_w = a0_w; p.a0_b = a0_b; p.a0_ln_g = a0_ln_g; p.a0_ln_b = a0_ln_b;
    p.alpha = alpha; p.sb_w = sb_w; p.sb_b = sb_b;
    p.cm_w1 = cm_w1; p.cm_b1 = cm_b1; p.cm_w2 = cm_w2; p.cm_b2 = cm_b2;
    p.fu_b1 = fu_b1; p.fu_b2 = fu_b2; p.fu_b3 = fu_b3; p.fu_b4 = fu_b4;
    p.ffn_b1 = ffn_b1; p.ffn_b2 = ffn_b2;

    p.opj     = ws;                              // 1024
    p.u0      = ws + 1024;                       // 16384 [v][1024][8]
    p.u1      = ws + 17408;                      // 16384
    p.u2      = ws + 33792;                      // 16384
    p.pkq     = ws + 50176;                      // 8192 [v][8][64][8]
    p.pqq     = ws + 58368;                      // 8192
    p.pvo     = ws + 66560;                      // 8192
    p.phirs   = ws + 74752;                      // 2048
    p.bias2   = ws + 76800;                      // 2048
    p.parts   = ws + 78848;                      // 128 (4 used)
    p.amap_bf = (ushort_t*)(ws + 78976);         // 65536 ush
    p.h1_bf   = (ushort_t*)(ws + 111744);        // 524288 ush
    p.h2_bf   = (ushort_t*)(ws + 373888);        // 524288 ush
    p.fbuf_bf = (ushort_t*)(ws + 636032);        // 196608 ush
    p.hA_bf   = (ushort_t*)(ws + 734336);        // 131072 ush
    p.hB_bf   = (ushort_t*)(ws + 799872);        // 262144 ush
    p.w_fu1t  = (ushort_t*)(ws + 930944);        // 98304  [256][384]
    p.w_fu2t  = (ushort_t*)(ws + 980096);        // 131072 [512][256]
    p.w_fu3t  = (ushort_t*)(ws + 1045632);       // 131072 [256][512]
    p.w_ffn1t = (ushort_t*)(ws + 1111168);       // 65536  [v][512][64]
    p.w_ffn2t = (ushort_t*)(ws + 1143936);       // 524288 [v][512][512]
    p.w_ffn3t = (ushort_t*)(ws + 1406080);       // 65536  [v][64][512]
    p.Abig    = (ushort_t*)(ws + 1438848);       // 196608 [512][384]
    p.Bbig    = (ushort_t*)(ws + 1537152);       // 786432 [2048][384]
    p.obuf    = ws + 1930368;                    // 65536 fp32 [v][512][64]
    p.out     = (float*)d_out;

    CvtArgs ca;
    auto set = [&](int i, const float* s, ushort_t* dst, int K, int N,
                   int mode, int ldd, int coff) {
        ca.d[i].src = s; ca.d[i].dst = dst; ca.d[i].K = K; ca.d[i].N = N;
        ca.d[i].mode = mode; ca.d[i].ldd = ldd; ca.d[i].coff = coff;
    };
    // ---- stage0 tiles [0, 72): weights consumed in stage1/stage2-start ----
    set(0,  fu_w1,           p.w_fu1t,           384, 256,  0, 384, 0);   // 24
    set(1,  fu_w2,           p.w_fu2t,           256, 512,  0, 256, 0);   // 32
    set(2,  ffn_w1,          p.w_ffn1t,          64,  512,  0, 64,  0);   // 8
    set(3,  ffn_w1 + 32768,  p.w_ffn1t + 32768,  64,  512,  0, 64,  0);   // 8
    // ---- stage1 tiles [72, 360): consumed in stage2/3/4 ----
    set(4,  fu_w4,           p.Bbig,             256, 2048, 0, 384, 128); // 128
    set(5,  Phi,             p.Bbig,             0,    0,   2, 384, 0);   // 16 (v=0)
    set(6,  Phi + 65536,     p.Bbig + (long)1024*384, 1024, 0, 2, 384, 64); // 16 (v=1)
    set(7,  ffn_w2,          p.w_ffn2t,          512, 512,  0, 512, 0);   // 64
    set(8,  ffn_w2 + 262144, p.w_ffn2t + 262144, 512, 512,  0, 512, 0);   // 64
    // ---- stage2 tiles [360, 408): consumed in stage3 ----
    set(9,  fu_w3,           p.w_fu3t,           512, 256,  0, 512, 0);   // 32
    set(10, ffn_w3,          p.w_ffn3t,          512, 64,   0, 512, 0);   // 8
    set(11, ffn_w3 + 32768,  p.w_ffn3t + 32768,  512, 64,   0, 512, 0);   // 8
    const int tl[12] = {24,32,8,8, 128,16,16,64,64, 32,8,8};
    ca.cum[0] = 0;
    for (int i = 0; i < 12; ++i) ca.cum[i+1] = ca.cum[i] + tl[i];

    stage0_k <<<888, 256, 16896, stream>>>(p, ca);
    stage1_k <<<496, 256, 20480, stream>>>(p, ca);
    stage2_k <<<256, 256, 20480, stream>>>(p, ca);
    stage3_k <<<49,  256, 20480, stream>>>(p);
    stage3b_k<<<256, 256, 0,     stream>>>(p);
    stage4_k <<<256, 256, 20480, stream>>>(p);
}